// Round 8
// baseline (203.508 us; speedup 1.0000x reference)
//
#include <hip/hip_runtime.h>
#include <hip/hip_bf16.h>
#include <stdint.h>

#define HD 128
#define NB 8
#define TQN 512
#define TKN 512
#define QT 8        // queries per block
#define KTILE 64
#define QSTR 132    // qp_s row stride (floats)
#define KBSTR 136   // bf16 tile row stride (ushorts): rows 16B-aligned

typedef __attribute__((ext_vector_type(8))) short short8;  // 8 bf16
typedef __attribute__((ext_vector_type(4))) float f32x4;   // MFMA C/D
typedef __attribute__((ext_vector_type(2))) float f32x2;   // packed-f32 pair

#if __has_builtin(__builtin_elementwise_fma)
#define FMA2(a,b,c) __builtin_elementwise_fma((a),(b),(c))
#else
#define FMA2(a,b,c) ((a)*(b)+(c))
#endif

static __device__ __forceinline__ float lo16(uint32_t w){
  union { uint32_t i; float f; } v; v.i = w << 16; return v.f;
}
static __device__ __forceinline__ float hi16(uint32_t w){
  union { uint32_t i; float f; } v; v.i = w & 0xffff0000u; return v.f;
}
static __device__ __forceinline__ float bf2f(unsigned short u){
  union { uint32_t i; float f; } v; v.i = ((uint32_t)u) << 16; return v.f;
}
static __device__ __forceinline__ uint32_t f2bf(float f){   // RNE
  union { float f; uint32_t i; } v; v.f = f;
  uint32_t u = v.i;
  u += 0x7fffu + ((u >> 16) & 1u);
  return u >> 16;
}
template<int CTRL>
static __device__ __forceinline__ float dpp_add(float x){
  union { float f; int i; } u; u.f = x;
  int y = __builtin_amdgcn_update_dpp(0, u.i, CTRL, 0xf, 0xf, true);
  union { int i; float f; } w; w.i = y;
  return x + w.f;
}
static __device__ __forceinline__ float ld1(const void* p, size_t idx, bool f32){
  return f32 ? ((const float*)p)[idx] : bf2f(((const unsigned short*)p)[idx]);
}
static __device__ __forceinline__ short8 ld8bf(const void* p, size_t idx, bool f32){
  short8 r;
  if (f32){
    const float* s = (const float*)p + idx;
    #pragma unroll
    for (int i = 0; i < 8; i++) r[i] = (short)f2bf(s[i]);
  } else {
    r = *(const short8*)((const unsigned short*)p + idx);
  }
  return r;
}

// ================= R8: single fused kernel =================
// proj (55us launch-latency-bound kernel) fused into the attn block:
// Q-proj (waves 0-7, 32 MFMA) -> qp_s E-values; K-proj per key-tile on
// the otherwise-idle MFMA pipe, pipelined with score compute:
//   { KPROJ(raw->kc) | prefetch raw kt+2 | SCORES(E[kt]) | EWRITE E[kt+1] }
// E = clamp(exp(2*proj),2^-13,2^13); score contribution
// va*tanh(q+k) = va - 2*va/(Eq*Ek+1) with single-rcp quad fusion; the
// softmax-invariant constant sum(va)+Vb is dropped.
// 1024 thr = 16 waves (qr=wv&7, hh=wv>>3); LDS ~56KB -> 2 blk/CU.
__global__ __launch_bounds__(1024, 8) void fused2_kernel(
    const void* __restrict__ queries, const void* __restrict__ keys,
    const void* __restrict__ Wa_w,   const void* __restrict__ Wa_b,
    const void* __restrict__ Ua_w,   const void* __restrict__ Ua_b,
    const void* __restrict__ Va_w,
    void* __restrict__ out)
{
  __shared__ __align__(16) unsigned short kraw_s[KTILE*KBSTR];   // 17.4KB raw keys bf16
  __shared__ __align__(16) unsigned short es[2][KTILE*KBSTR];    // 34.8KB E-tiles bf16
  __shared__ float qp_s[QT*QSTR];                                // 4.2KB q E-values
  __shared__ unsigned int flg_s[8];

  const int tid = threadIdx.x;
  // XCD-batch affinity: batch = blockIdx&7 (64 blocks/batch on one XCD L2).
  const int b     = blockIdx.x & 7;
  const int qbase = (blockIdx.x >> 3) * QT;

  if (tid < 8) flg_s[tid] = 0;
  __syncthreads();
  {
    const void* ptrs[7] = {queries, keys, Wa_w, Wa_b, Ua_w, Ua_b, Va_w};
    const int grp = tid >> 5;
    const int l   = tid & 31;
    if (grp < 7){
      const unsigned short* p = (const unsigned short*)ptrs[grp];
      unsigned short a = p[2*l], c = p[64 + 2*l];
      if (((a >> 7) & 0xFF) > 0x90 || ((c >> 7) & 0xFF) > 0x90)
        atomicOr(&flg_s[grp], 1u);
    }
  }
  __syncthreads();
  const bool fQ  = flg_s[0] != 0;   // also selects OUTPUT dtype
  const bool fK  = flg_s[1] != 0;
  const bool fWw = flg_s[2] != 0;
  const bool fWb = flg_s[3] != 0;
  const bool fUw = flg_s[4] != 0;
  const bool fUb = flg_s[5] != 0;
  const bool fVw = flg_s[6] != 0;

  const int lane = tid & 63;
  const int wv   = tid >> 6;        // wave id 0..15
  const int qr   = wv & 7;          // q-row (phase 1/2 role)
  const int hh   = wv >> 3;         // h-half 0/1
  const int ln   = lane & 15;
  const int quad = lane >> 4;
  const int s8   = lane >> 3;       // key-slot 0..7
  const int o8   = lane & 7;        // h-octant
  const int kh0  = (wv & 7) * 16;   // K-proj: output h-col slice
  const int rh   = wv >> 3;         // K-proj: key-row half (rows rh*32+[0,32))

  // ---- Q-proj (waves 0-7): 8 rows x 128 -> qp_s E-values ----
  if (wv < 8){
    const int h0 = wv * 16;
    const size_t qrow = (size_t)(b*TQN + qbase + (ln & 7))*HD;
    f32x4 c = {0.f,0.f,0.f,0.f};
    #pragma unroll
    for (int ks = 0; ks < 4; ks++){
      short8 a = ld8bf(queries, qrow + ks*32 + quad*8, fQ);
      short8 w = ld8bf(Wa_w, (size_t)(h0 + ln)*HD + ks*32 + quad*8, fWw);
      c = __builtin_amdgcn_mfma_f32_16x16x32_bf16(a, w, c, 0,0,0);
    }
    const float wb = ld1(Wa_b, h0 + ln, fWb);
    #pragma unroll
    for (int r4 = 0; r4 < 4; r4++){
      const int row = quad*4 + r4;
      if (row < QT){
        const float e = __builtin_amdgcn_exp2f((c[r4] + wb) * 2.8853900817779268f);
        qp_s[row*QSTR + h0 + ln] = fminf(fmaxf(e, 0x1p-13f), 0x1p13f);
      }
    }
  }
  // ---- all waves: Ua slice for K-proj ----
  short8 ub[4];
  float ubias;
  {
    #pragma unroll
    for (int ks = 0; ks < 4; ks++)
      ub[ks] = ld8bf(Ua_w, (size_t)(kh0 + ln)*HD + ks*32 + quad*8, fUw);
    ubias = ld1(Ua_b, kh0 + ln, fUb);
  }
  // ---- stage raw keys tile 0 -> kraw_s ----
  if (fK){
    const float4* src = (const float4*)((const float*)keys + (size_t)(b*TKN)*HD);
    #pragma unroll
    for (int j = 0; j < 2; j++){
      const int f = tid + 1024*j;
      float4 v = src[f];
      const int k = f >> 5, h = (f & 31)*4;
      uint2 p;
      p.x = f2bf(v.x) | (f2bf(v.y) << 16);
      p.y = f2bf(v.z) | (f2bf(v.w) << 16);
      *(uint2*)(kraw_s + k*KBSTR + h) = p;
    }
  } else {
    const uint4* src = (const uint4*)((const unsigned short*)keys + (size_t)(b*TKN)*HD);
    const int k = tid >> 4, h = (tid & 15)*8;
    *(uint4*)(kraw_s + k*KBSTR + h) = src[tid];
  }
  __syncthreads();   // qp_s + kraw(t0) ready

  // ---- per-lane hoists: Eq + (-2*va), h = o8*16 + hh*8 + [0,8) ----
  f32x2 eq2[4], a2[4];
  {
    const float* qsrc = qp_s + qr*QSTR + o8*16 + hh*8;
    #pragma unroll
    for (int c = 0; c < 2; c++){
      const float4 t = *(const float4*)(qsrc + c*4);
      eq2[2*c].x = t.x; eq2[2*c].y = t.y;
      eq2[2*c+1].x = t.z; eq2[2*c+1].y = t.w;
      a2[2*c].x   = -2.0f * ld1(Va_w, o8*16 + hh*8 + c*4 + 0, fVw);
      a2[2*c].y   = -2.0f * ld1(Va_w, o8*16 + hh*8 + c*4 + 1, fVw);
      a2[2*c+1].x = -2.0f * ld1(Va_w, o8*16 + hh*8 + c*4 + 2, fVw);
      a2[2*c+1].y = -2.0f * ld1(Va_w, o8*16 + hh*8 + c*4 + 3, fVw);
    }
  }
  f32x2 one2; one2.x = 1.f; one2.y = 1.f;

  // ---- prologue: project tile 0 -> es[0]; prefetch raw t1 ----
  uint4 st0, st1;
  {
    f32x4 kc[2];
    kc[0] = (f32x4){0.f,0.f,0.f,0.f};
    kc[1] = (f32x4){0.f,0.f,0.f,0.f};
    #pragma unroll
    for (int ks = 0; ks < 4; ks++){
      short8 af0 = *(const short8*)(kraw_s + (rh*32      + ln)*KBSTR + ks*32 + quad*8);
      short8 af1 = *(const short8*)(kraw_s + (rh*32 + 16 + ln)*KBSTR + ks*32 + quad*8);
      kc[0] = __builtin_amdgcn_mfma_f32_16x16x32_bf16(af0, ub[ks], kc[0], 0,0,0);
      kc[1] = __builtin_amdgcn_mfma_f32_16x16x32_bf16(af1, ub[ks], kc[1], 0,0,0);
    }
    if (fK){
      const uint4* src = (const uint4*)((const float*)keys + (size_t)(b*TKN + KTILE)*HD);
      st0 = src[tid]; st1 = src[tid + 1024];
    } else {
      const uint4* src = (const uint4*)((const unsigned short*)keys + (size_t)(b*TKN + KTILE)*HD);
      st0 = src[tid];
    }
    #pragma unroll
    for (int mt = 0; mt < 2; mt++)
      #pragma unroll
      for (int r4 = 0; r4 < 4; r4++){
        const int row = rh*32 + mt*16 + quad*4 + r4;
        const float e = __builtin_amdgcn_exp2f((kc[mt][r4] + ubias) * 2.8853900817779268f);
        es[0][row*KBSTR + kh0 + ln] =
            (unsigned short)f2bf(fminf(fmaxf(e, 0x1p-13f), 0x1p13f));
      }
  }
  __syncthreads();   // es[0] ready; kraw(t0) reads done
  // write raw t1
  if (fK){
    #pragma unroll
    for (int j = 0; j < 2; j++){
      uint4 v = j ? st1 : st0;
      const int f = tid + 1024*j;
      const int k = f >> 5, h = (f & 31)*4;
      uint2 p;
      p.x = f2bf(__uint_as_float(v.x)) | (f2bf(__uint_as_float(v.y)) << 16);
      p.y = f2bf(__uint_as_float(v.z)) | (f2bf(__uint_as_float(v.w)) << 16);
      *(uint2*)(kraw_s + k*KBSTR + h) = p;
    }
  } else {
    *(uint4*)(kraw_s + (tid >> 4)*KBSTR + (tid & 15)*8) = st0;
  }
  __syncthreads();   // kraw = t1

  // ---- main loop: 8 key tiles ----
  float sc8[8];
  for (int kt = 0; kt < 8; kt++){
    f32x4 kc[2];
    if (kt < 7){   // project tile kt+1 (raw in kraw_s)
      kc[0] = (f32x4){0.f,0.f,0.f,0.f};
      kc[1] = (f32x4){0.f,0.f,0.f,0.f};
      #pragma unroll
      for (int ks = 0; ks < 4; ks++){
        short8 af0 = *(const short8*)(kraw_s + (rh*32      + ln)*KBSTR + ks*32 + quad*8);
        short8 af1 = *(const short8*)(kraw_s + (rh*32 + 16 + ln)*KBSTR + ks*32 + quad*8);
        kc[0] = __builtin_amdgcn_mfma_f32_16x16x32_bf16(af0, ub[ks], kc[0], 0,0,0);
        kc[1] = __builtin_amdgcn_mfma_f32_16x16x32_bf16(af1, ub[ks], kc[1], 0,0,0);
      }
      if (kt < 6){   // prefetch raw tile kt+2
        if (fK){
          const uint4* src = (const uint4*)((const float*)keys + (size_t)(b*TKN + (kt+2)*KTILE)*HD);
          st0 = src[tid]; st1 = src[tid + 1024];
        } else {
          const uint4* src = (const uint4*)((const unsigned short*)keys + (size_t)(b*TKN + (kt+2)*KTILE)*HD);
          st0 = src[tid];
        }
      }
    }
    // scores from es[kt&1]
    {
      const unsigned short* buf = &es[kt & 1][0];
      float acc[8];
      #pragma unroll
      for (int i = 0; i < 8; i++){
        const unsigned short* tk = buf + (i*8 + s8)*KBSTR + o8*16 + hh*8;
        const uint4 v = *(const uint4*)tk;
        float acci = 0.f;
        {  // quad 0: elements 0..3
          f32x2 kv0; kv0.x = lo16(v.x); kv0.y = hi16(v.x);
          f32x2 kv1; kv1.x = lo16(v.y); kv1.y = hi16(v.y);
          f32x2 x01 = FMA2(eq2[0], kv0, one2);
          f32x2 x23 = FMA2(eq2[1], kv1, one2);
          f32x2 xs01; xs01.x = x01.y; xs01.y = x01.x;
          f32x2 xs23; xs23.x = x23.y; xs23.y = x23.x;
          f32x2 s01 = a2[0] * xs01;
          f32x2 s23 = a2[1] * xs23;
          const float p01 = x01.x * x01.y;
          const float p23 = x23.x * x23.y;
          const float n01 = s01.x + s01.y;
          const float n23 = s23.x + s23.y;
          const float P   = p01 * p23;
          const float N   = fmaf(n01, p23, n23 * p01);
          acci = fmaf(N, __builtin_amdgcn_rcpf(P), acci);
        }
        {  // quad 1: elements 4..7
          f32x2 kv0; kv0.x = lo16(v.z); kv0.y = hi16(v.z);
          f32x2 kv1; kv1.x = lo16(v.w); kv1.y = hi16(v.w);
          f32x2 x01 = FMA2(eq2[2], kv0, one2);
          f32x2 x23 = FMA2(eq2[3], kv1, one2);
          f32x2 xs01; xs01.x = x01.y; xs01.y = x01.x;
          f32x2 xs23; xs23.x = x23.y; xs23.y = x23.x;
          f32x2 s01 = a2[2] * xs01;
          f32x2 s23 = a2[3] * xs23;
          const float p01 = x01.x * x01.y;
          const float p23 = x23.x * x23.y;
          const float n01 = s01.x + s01.y;
          const float n23 = s23.x + s23.y;
          const float P   = p01 * p23;
          const float N   = fmaf(n01, p23, n23 * p01);
          acci = fmaf(N, __builtin_amdgcn_rcpf(P), acci);
        }
        acc[i] = acci;
      }
      #pragma unroll
      for (int i = 0; i < 8; i++){
        float a = acc[i];
        a = dpp_add<0xB1>(a);
        a = dpp_add<0x4E>(a);
        a = dpp_add<0x141>(a);
        acc[i] = a;
      }
      float sc = acc[0];
      #pragma unroll
      for (int i = 1; i < 8; i++) sc = (o8 == i) ? acc[i] : sc;
      sc8[kt] = sc;   // PARTIAL score (h-half hh) for key kt*64 + o8*8 + s8
    }
    if (kt < 7){   // write E(kt+1)
      #pragma unroll
      for (int mt = 0; mt < 2; mt++)
        #pragma unroll
        for (int r4 = 0; r4 < 4; r4++){
          const int row = rh*32 + mt*16 + quad*4 + r4;
          const float e = __builtin_amdgcn_exp2f((kc[mt][r4] + ubias) * 2.8853900817779268f);
          es[(kt+1) & 1][row*KBSTR + kh0 + ln] =
              (unsigned short)f2bf(fminf(fmaxf(e, 0x1p-13f), 0x1p13f));
        }
    }
    __syncthreads();   // publish E(kt+1); end reads of kraw & es[kt&1]
    if (kt < 6){       // publish raw tile kt+2
      if (fK){
        #pragma unroll
        for (int j = 0; j < 2; j++){
          uint4 v = j ? st1 : st0;
          const int f = tid + 1024*j;
          const int k = f >> 5, h = (f & 31)*4;
          uint2 p;
          p.x = f2bf(__uint_as_float(v.x)) | (f2bf(__uint_as_float(v.y)) << 16);
          p.y = f2bf(__uint_as_float(v.z)) | (f2bf(__uint_as_float(v.w)) << 16);
          *(uint2*)(kraw_s + k*KBSTR + h) = p;
        }
      } else {
        *(uint4*)(kraw_s + (tid >> 4)*KBSTR + (tid & 15)*8) = st0;
      }
      __syncthreads();
    }
  }

  // ---- combine h-halves + softmax (register key-order) ----
  float* psc = (float*)&es[0][0];   // E-tiles dead: 17.4KB scratch
  float* wgt = (float*)&es[1][0];   // 16KB weights [8][512]
  if (hh == 1){
    #pragma unroll
    for (int kt = 0; kt < 8; kt++)
      psc[qr*TKN + kt*64 + o8*8 + s8] = sc8[kt];
  }
  __syncthreads();
  if (hh == 0){
    float vals[8];
    float m = -1e30f;
    #pragma unroll
    for (int j = 0; j < 8; j++){
      vals[j] = sc8[j] + psc[qr*TKN + j*64 + o8*8 + s8];
      m = fmaxf(m, vals[j]);
    }
    #pragma unroll
    for (int o = 32; o > 0; o >>= 1) m = fmaxf(m, __shfl_xor(m, o));
    float sum = 0.f;
    #pragma unroll
    for (int j = 0; j < 8; j++){
      vals[j] = __builtin_amdgcn_exp2f((vals[j]-m)*1.4426950408889634f);
      sum += vals[j];
    }
    #pragma unroll
    for (int o = 32; o > 0; o >>= 1) sum += __shfl_xor(sum, o);
    const float inv = __builtin_amdgcn_rcpf(sum);
    // lane-transpose via bpermute -> coalesced stores
    const int psrc = ((((lane & 7) << 3) | (lane >> 3)) << 2);
    const size_t wbase = (size_t)NB*TQN*HD + (size_t)(b*TQN + qbase + qr)*TKN;
    float* wrow = wgt + qr*TKN;
    #pragma unroll
    for (int j = 0; j < 8; j++){
      union { float f; int i; } u; u.f = vals[j]*inv;
      union { int i; float f; } t; t.i = __builtin_amdgcn_ds_bpermute(psrc, u.i);
      wrow[j*64 + lane] = t.f;
      if (fQ) ((float*)out)[wbase + j*64 + lane] = t.f;
      else    ((unsigned short*)out)[wbase + j*64 + lane] = (unsigned short)f2bf(t.f);
    }
  }
  __syncthreads();

  // ---- phase 3: contexts = weights @ keys, DIRECT from L2 ----
  // p2 = wv&3 -> rows {2p2, 2p2+1}; g2 = wv>>2 -> key quarter.
  {
    const int p2 = wv & 3;
    const int g2 = wv >> 2;
    const int h0 = ln * 8;
    f32x2 a0v[4], a1v[4];
    #pragma unroll
    for (int t = 0; t < 4; t++){
      a0v[t].x = 0.f; a0v[t].y = 0.f;
      a1v[t].x = 0.f; a1v[t].y = 0.f;
    }
    const float* w0rb = wgt + (2*p2)*TKN;
    if (!fK){
      const unsigned short* kb = (const unsigned short*)keys
          + (size_t)(b*TKN)*HD + h0;
      #pragma unroll
      for (int t = 0; t < 2; t++){
        const int kt = g2*2 + t;
        const float* w0r = w0rb + kt*KTILE;
        const float* w1r = w0r + TKN;
        #pragma unroll
        for (int i = 0; i < 16; i++){
          const int k = i*4 + quad;
          const uint4 v = *(const uint4*)(kb + (size_t)(kt*KTILE + k)*HD);
          const float w0 = w0r[k];
          const float w1 = w1r[k];
          f32x2 c0; c0.x = lo16(v.x); c0.y = hi16(v.x);
          f32x2 c1; c1.x = lo16(v.y); c1.y = hi16(v.y);
          f32x2 c2; c2.x = lo16(v.z); c2.y = hi16(v.z);
          f32x2 c3; c3.x = lo16(v.w); c3.y = hi16(v.w);
          f32x2 w0v; w0v.x = w0; w0v.y = w0;
          f32x2 w1v; w1v.x = w1; w1v.y = w1;
          a0v[0] = FMA2(w0v, c0, a0v[0]); a0v[1] = FMA2(w0v, c1, a0v[1]);
          a0v[2] = FMA2(w0v, c2, a0v[2]); a0v[3] = FMA2(w0v, c3, a0v[3]);
          a1v[0] = FMA2(w1v, c0, a1v[0]); a1v[1] = FMA2(w1v, c1, a1v[1]);
          a1v[2] = FMA2(w1v, c2, a1v[2]); a1v[3] = FMA2(w1v, c3, a1v[3]);
        }
      }
    } else {
      const float* kb = (const float*)keys + (size_t)(b*TKN)*HD + h0;
      #pragma unroll
      for (int t = 0; t < 2; t++){
        const int kt = g2*2 + t;
        const float* w0r = w0rb + kt*KTILE;
        const float* w1r = w0r + TKN;
        #pragma unroll
        for (int i = 0; i < 16; i++){
          const int k = i*4 + quad;
          const float* kr = kb + (size_t)(kt*KTILE + k)*HD;
          const float4 k0 = *(const float4*)(kr);
          const float4 k1 = *(const float4*)(kr + 4);
          const float w0 = w0r[k];
          const float w1 = w1r[k];
          f32x2 c0; c0.x = k0.x; c0.y = k0.y;
          f32x2 c1; c1.x = k0.z; c1.y = k0.w;
          f32x2 c2; c2.x = k1.x; c2.y = k1.y;
          f32x2 c3; c3.x = k1.z; c3.y = k1.w;
          f32x2 w0v; w0v.x = w0; w0v.y = w0;
          f32x2 w1v; w1v.x = w1; w1v.y = w1;
          a0v[0] = FMA2(w0v, c0, a0v[0]); a0v[1] = FMA2(w0v, c1, a0v[1]);
          a0v[2] = FMA2(w0v, c2, a0v[2]); a0v[3] = FMA2(w0v, c3, a0v[3]);
          a1v[0] = FMA2(w1v, c0, a1v[0]); a1v[1] = FMA2(w1v, c1, a1v[1]);
          a1v[2] = FMA2(w1v, c2, a1v[2]); a1v[3] = FMA2(w1v, c3, a1v[3]);
        }
      }
    }
    float a0[8], a1[8];
    #pragma unroll
    for (int t = 0; t < 4; t++){
      a0[2*t] = a0v[t].x; a0[2*t+1] = a0v[t].y;
      a1[2*t] = a1v[t].x; a1[2*t+1] = a1v[t].y;
    }
    #pragma unroll
    for (int t = 0; t < 8; t++){
      a0[t] += __shfl_xor(a0[t], 16); a0[t] += __shfl_xor(a0[t], 32);
      a1[t] += __shfl_xor(a1[t], 16); a1[t] += __shfl_xor(a1[t], 32);
    }
    __syncthreads();                  // all waves done reading wgt
    float* part = psc;                // 17.4KB scratch (3072 floats used)
    if (g2 > 0 && quad == 0){
      const int base = ((g2-1)*8 + 2*p2)*HD + h0;
      *(float4*)(part + base       ) = (float4){a0[0],a0[1],a0[2],a0[3]};
      *(float4*)(part + base + 4   ) = (float4){a0[4],a0[5],a0[6],a0[7]};
      *(float4*)(part + base + HD  ) = (float4){a1[0],a1[1],a1[2],a1[3]};
      *(float4*)(part + base + HD+4) = (float4){a1[4],a1[5],a1[6],a1[7]};
    }
    __syncthreads();
    if (g2 == 0 && quad == 0){
      #pragma unroll
      for (int gg = 0; gg < 3; gg++){
        const int base = (gg*8 + 2*p2)*HD + h0;
        const float4 q00 = *(const float4*)(part + base);
        const float4 q01 = *(const float4*)(part + base + 4);
        const float4 q10 = *(const float4*)(part + base + HD);
        const float4 q11 = *(const float4*)(part + base + HD + 4);
        a0[0]+=q00.x; a0[1]+=q00.y; a0[2]+=q00.z; a0[3]+=q00.w;
        a0[4]+=q01.x; a0[5]+=q01.y; a0[6]+=q01.z; a0[7]+=q01.w;
        a1[0]+=q10.x; a1[1]+=q10.y; a1[2]+=q10.z; a1[3]+=q10.w;
        a1[4]+=q11.x; a1[5]+=q11.y; a1[6]+=q11.z; a1[7]+=q11.w;
      }
      const size_t crow0 = (size_t)(b*TQN + qbase + 2*p2    )*HD + h0;
      const size_t crow1 = (size_t)(b*TQN + qbase + 2*p2 + 1)*HD + h0;
      if (fQ){
        float* oc = (float*)out;
        *(float4*)(oc + crow0)     = (float4){a0[0],a0[1],a0[2],a0[3]};
        *(float4*)(oc + crow0 + 4) = (float4){a0[4],a0[5],a0[6],a0[7]};
        *(float4*)(oc + crow1)     = (float4){a1[0],a1[1],a1[2],a1[3]};
        *(float4*)(oc + crow1 + 4) = (float4){a1[4],a1[5],a1[6],a1[7]};
      } else {
        uint4 o0, o1;
        o0.x = f2bf(a0[0]) | (f2bf(a0[1]) << 16);
        o0.y = f2bf(a0[2]) | (f2bf(a0[3]) << 16);
        o0.z = f2bf(a0[4]) | (f2bf(a0[5]) << 16);
        o0.w = f2bf(a0[6]) | (f2bf(a0[7]) << 16);
        o1.x = f2bf(a1[0]) | (f2bf(a1[1]) << 16);
        o1.y = f2bf(a1[2]) | (f2bf(a1[3]) << 16);
        o1.z = f2bf(a1[4]) | (f2bf(a1[5]) << 16);
        o1.w = f2bf(a1[6]) | (f2bf(a1[7]) << 16);
        *(uint4*)((unsigned short*)out + crow0) = o0;
        *(uint4*)((unsigned short*)out + crow1) = o1;
      }
    }
  }
}

extern "C" void kernel_launch(void* const* d_in, const int* in_sizes, int n_in,
                              void* d_out, int out_size, void* d_ws, size_t ws_size,
                              hipStream_t stream) {
  (void)in_sizes; (void)n_in; (void)out_size; (void)d_ws; (void)ws_size;
  fused2_kernel<<<512, 1024, 0, stream>>>(d_in[0], d_in[1], d_in[2], d_in[3],
                                          d_in[4], d_in[5], d_in[6], d_out);
}

// Round 9
// 143.738 us; speedup vs baseline: 1.4158x; 1.4158x over previous
//
#include <hip/hip_runtime.h>
#include <hip/hip_bf16.h>
#include <stdint.h>

#define HD 128
#define NB 8
#define TQN 512
#define TKN 512
#define QT 8        // queries per block (K2)
#define KTILE 64
#define KSTR 132    // f32 stride (fallback kp_s)
#define QSTR 132
#define KBSTR 136   // bf16 tile row stride (ushorts): rows 16B-aligned
#define FQT 8       // fallback queries per block

typedef __attribute__((ext_vector_type(8))) short short8;  // 8 bf16
typedef __attribute__((ext_vector_type(4))) float f32x4;   // MFMA C/D
typedef __attribute__((ext_vector_type(2))) float f32x2;   // packed-f32 pair

#if __has_builtin(__builtin_elementwise_fma)
#define FMA2(a,b,c) __builtin_elementwise_fma((a),(b),(c))
#else
#define FMA2(a,b,c) ((a)*(b)+(c))
#endif

static __device__ __forceinline__ float lo16(uint32_t w){
  union { uint32_t i; float f; } v; v.i = w << 16; return v.f;
}
static __device__ __forceinline__ float hi16(uint32_t w){
  union { uint32_t i; float f; } v; v.i = w & 0xffff0000u; return v.f;
}
static __device__ __forceinline__ float bf2f(unsigned short u){
  union { uint32_t i; float f; } v; v.i = ((uint32_t)u) << 16; return v.f;
}
static __device__ __forceinline__ uint32_t f2bf(float f){   // RNE
  union { float f; uint32_t i; } v; v.f = f;
  uint32_t u = v.i;
  u += 0x7fffu + ((u >> 16) & 1u);
  return u >> 16;
}
static __device__ __forceinline__ float tanh_acc(float x){
  float e = __builtin_amdgcn_exp2f(x * 2.8853900817779268f);
  return fmaf(-2.0f, __builtin_amdgcn_rcpf(e + 1.0f), 1.0f);
}
template<int CTRL>
static __device__ __forceinline__ float dpp_add(float x){
  union { float f; int i; } u; u.f = x;
  int y = __builtin_amdgcn_update_dpp(0, u.i, CTRL, 0xf, 0xf, true);
  union { int i; float f; } w; w.i = y;
  return x + w.f;
}
static __device__ __forceinline__ float ld1(const void* p, size_t idx, bool f32){
  return f32 ? ((const float*)p)[idx] : bf2f(((const unsigned short*)p)[idx]);
}
static __device__ __forceinline__ short8 ld8bf(const void* p, size_t idx, bool f32){
  short8 r;
  if (f32){
    const float* s = (const float*)p + idx;
    #pragma unroll
    for (int i = 0; i < 8; i++) r[i] = (short)f2bf(s[i]);
  } else {
    r = *(const short8*)((const unsigned short*)p + idx);
  }
  return r;
}

// ================= K1: KEYS-ONLY projection + exp precompute =================
// Stores Ek = clamp(exp(2*(k@Ua.T+Ub)), 2^-13, 2^13) as bf16.
// Q-projection moved into attn_kernel (it only needs the block's 8 rows).
// 256 blocks x 256 thr: b7=blockIdx&7 keeps batch->XCD affinity.
__global__ __launch_bounds__(256) void kproj_kernel(
    const void* __restrict__ keys,
    const void* __restrict__ Ua_w, const void* __restrict__ Ua_b,
    unsigned short* __restrict__ tk_gb)
{
  __shared__ unsigned int flg_s[4];
  const int tid = threadIdx.x;
  if (tid < 4) flg_s[tid] = 0;
  __syncthreads();
  {
    const void* ptrs[3] = {keys, Ua_w, Ua_b};
    const int grp = tid >> 5;
    const int l   = tid & 31;
    if (grp < 3){
      const unsigned short* p = (const unsigned short*)ptrs[grp];
      unsigned short a = p[2*l], c = p[64 + 2*l];
      if (((a >> 7) & 0xFF) > 0x90 || ((c >> 7) & 0xFF) > 0x90)
        atomicOr(&flg_s[grp], 1u);
    }
  }
  __syncthreads();
  const bool fK  = flg_s[0] != 0;
  const bool fUw = flg_s[1] != 0;
  const bool fUb = flg_s[2] != 0;

  const int lane = tid & 63, wv = tid >> 6, ln = lane & 15, quad = lane >> 4;
  const int b7  = blockIdx.x & 7;
  const int idx = blockIdx.x >> 3;   // 0..31
  const int r   = b7*TKN + idx*16;

  short8 a[4];
  #pragma unroll
  for (int ks = 0; ks < 4; ks++)
    a[ks] = ld8bf(keys, (size_t)(r + ln)*HD + ks*32 + quad*8, fK);

  #pragma unroll
  for (int nt = 0; nt < 2; nt++){
    const int h0 = (2*wv + nt)*16;
    f32x4 c = {0.f,0.f,0.f,0.f};
    #pragma unroll
    for (int ks = 0; ks < 4; ks++)
      c = __builtin_amdgcn_mfma_f32_16x16x32_bf16(
            a[ks], ld8bf(Ua_w, (size_t)(h0 + ln)*HD + ks*32 + quad*8, fUw), c, 0,0,0);
    const float wb = ld1(Ua_b, h0 + ln, fUb);
    #pragma unroll
    for (int r4 = 0; r4 < 4; r4++){  // D: col=ln, row=quad*4+r4
      const float e = __builtin_amdgcn_exp2f((c[r4] + wb) * 2.8853900817779268f);
      tk_gb[(size_t)(r + quad*4 + r4)*HD + h0 + ln] =
          (unsigned short)f2bf(fminf(fmaxf(e, 0x1p-13f), 0x1p13f));
    }
  }
}

// ================= K2: Q-proj + scores + softmax + contexts =================
// R9 = R7 structure (double-buffered bf16 tiles, 1 barrier/tile) with
// Q-projection fused in (waves 0-7, 32 MFMA -> qp_s E-values).
// QT=8, grid 512, 1024 thr = 16 waves (qr=wv&7, hh=wv>>3);
// LDS = 2*17KB tiles + 16KB wgt + 4.2KB qp ~ 55.5KB -> 2 blk/CU.
__global__ __launch_bounds__(1024, 8) void attn_kernel(
    const void* __restrict__ queries, const void* __restrict__ keys,
    const void* __restrict__ Wa_w,   const void* __restrict__ Wa_b,
    const void* __restrict__ Va_w,
    const unsigned short* __restrict__ tk_gb,
    void* __restrict__ out)
{
  __shared__ __align__(16) unsigned short tkb_s[2][KTILE*KBSTR]; // 2x17408B
  __shared__ float wgt_s[QT*TKN];                                // 16 KB
  __shared__ float qp_s[QT*QSTR];                                // 4.2 KB
  __shared__ unsigned int flg_s[8];

  const int tid = threadIdx.x;
  // XCD-batch affinity: batch = blockIdx&7 (64 blocks/batch on one XCD L2).
  const int b     = blockIdx.x & 7;
  const int qbase = (blockIdx.x >> 3) * QT;

  // tile-0 prefetch before flag check (hides latency); one uint4 = 8 bf16
  uint4 st;
  {
    const uint4* src = (const uint4*)(tk_gb + (size_t)(b*TKN)*HD);
    st = src[tid];   // row=tid>>4, h=(tid&15)*8
  }

  if (tid < 8) flg_s[tid] = 0;
  __syncthreads();
  {
    const void* ptrs[5] = {queries, keys, Wa_w, Wa_b, Va_w};
    const int grp = tid >> 5;
    const int l   = tid & 31;
    if (grp < 5){
      const unsigned short* p = (const unsigned short*)ptrs[grp];
      unsigned short a = p[2*l], c = p[64 + 2*l];
      if (((a >> 7) & 0xFF) > 0x90 || ((c >> 7) & 0xFF) > 0x90)
        atomicOr(&flg_s[grp], 1u);
    }
  }
  __syncthreads();
  const bool fQ  = flg_s[0] != 0;   // also selects OUTPUT dtype
  const bool fK  = flg_s[1] != 0;
  const bool fWw = flg_s[2] != 0;
  const bool fWb = flg_s[3] != 0;
  const bool fVw = flg_s[4] != 0;

  const int lane = tid & 63;
  const int wv   = tid >> 6;        // wave id 0..15
  const int qr   = wv & 7;          // q-row within block
  const int hh   = wv >> 3;         // h-half 0/1 (within each octant)
  const int ln   = lane & 15;
  const int quad = lane >> 4;
  const int s8   = lane >> 3;       // key-slot 0..7
  const int o8   = lane & 7;        // h-octant
  const int sk   = tid >> 4;        // staging key row
  const int shh  = (tid & 15) * 8;  // staging h start

  // ---- Q-proj (waves 0-7): 8 rows x 128 -> qp_s E-values ----
  // (proven in R8; rides the otherwise-idle MFMA pipe)
  if (wv < 8){
    const int h0 = wv * 16;
    const size_t qrow = (size_t)(b*TQN + qbase + (ln & 7))*HD;
    f32x4 c = {0.f,0.f,0.f,0.f};
    #pragma unroll
    for (int ks = 0; ks < 4; ks++){
      short8 a = ld8bf(queries, qrow + ks*32 + quad*8, fQ);
      short8 w = ld8bf(Wa_w, (size_t)(h0 + ln)*HD + ks*32 + quad*8, fWw);
      c = __builtin_amdgcn_mfma_f32_16x16x32_bf16(a, w, c, 0,0,0);
    }
    const float wb = ld1(Wa_b, h0 + ln, fWb);
    #pragma unroll
    for (int r4 = 0; r4 < 4; r4++){
      const int row = quad*4 + r4;
      if (row < QT){
        const float e = __builtin_amdgcn_exp2f((c[r4] + wb) * 2.8853900817779268f);
        qp_s[row*QSTR + h0 + ln] = fminf(fmaxf(e, 0x1p-13f), 0x1p13f);
      }
    }
  }

  // ======== phase 1: double-buffered, 1 barrier/tile ========
  // write tile 0 -> buf0
  *(uint4*)(&tkb_s[0][sk*KBSTR + shh]) = st;
  __syncthreads();   // tile0 + qp_s ready

  // per-lane hoists: 8 floats, h = o8*16 + hh*8 + [0,8)
  f32x2 eq2[4], a2[4];
  {
    const float* qsrc = qp_s + qr*QSTR + o8*16 + hh*8;
    #pragma unroll
    for (int c = 0; c < 2; c++){
      const float4 t = *(const float4*)(qsrc + c*4);
      eq2[2*c].x = t.x; eq2[2*c].y = t.y;
      eq2[2*c+1].x = t.z; eq2[2*c+1].y = t.w;
      a2[2*c].x   = -2.0f * ld1(Va_w, o8*16 + hh*8 + c*4 + 0, fVw);
      a2[2*c].y   = -2.0f * ld1(Va_w, o8*16 + hh*8 + c*4 + 1, fVw);
      a2[2*c+1].x = -2.0f * ld1(Va_w, o8*16 + hh*8 + c*4 + 2, fVw);
      a2[2*c+1].y = -2.0f * ld1(Va_w, o8*16 + hh*8 + c*4 + 3, fVw);
    }
  }
  f32x2 one2; one2.x = 1.f; one2.y = 1.f;

  float sc8[8];
  for (int kt = 0; kt < 8; kt++){
    if (kt < 7){
      const uint4* src = (const uint4*)(tk_gb + (size_t)(b*TKN + (kt+1)*KTILE)*HD);
      st = src[tid];
    }
    const unsigned short* buf = &tkb_s[kt & 1][0];

    float acc[8];
    #pragma unroll
    for (int i = 0; i < 8; i++){
      const unsigned short* tk = buf + (i*8 + s8)*KBSTR + o8*16 + hh*8;
      const uint4 v = *(const uint4*)tk;
      float acci = 0.f;
      {  // quad 0: elements 0..3 (v.x, v.y)
        f32x2 kv0; kv0.x = lo16(v.x); kv0.y = hi16(v.x);
        f32x2 kv1; kv1.x = lo16(v.y); kv1.y = hi16(v.y);
        f32x2 x01 = FMA2(eq2[0], kv0, one2);
        f32x2 x23 = FMA2(eq2[1], kv1, one2);
        f32x2 xs01; xs01.x = x01.y; xs01.y = x01.x;
        f32x2 xs23; xs23.x = x23.y; xs23.y = x23.x;
        f32x2 s01 = a2[0] * xs01;
        f32x2 s23 = a2[1] * xs23;
        const float p01 = x01.x * x01.y;
        const float p23 = x23.x * x23.y;
        const float n01 = s01.x + s01.y;
        const float n23 = s23.x + s23.y;
        const float P   = p01 * p23;
        const float N   = fmaf(n01, p23, n23 * p01);
        acci = fmaf(N, __builtin_amdgcn_rcpf(P), acci);
      }
      {  // quad 1: elements 4..7 (v.z, v.w)
        f32x2 kv0; kv0.x = lo16(v.z); kv0.y = hi16(v.z);
        f32x2 kv1; kv1.x = lo16(v.w); kv1.y = hi16(v.w);
        f32x2 x01 = FMA2(eq2[2], kv0, one2);
        f32x2 x23 = FMA2(eq2[3], kv1, one2);
        f32x2 xs01; xs01.x = x01.y; xs01.y = x01.x;
        f32x2 xs23; xs23.x = x23.y; xs23.y = x23.x;
        f32x2 s01 = a2[2] * xs01;
        f32x2 s23 = a2[3] * xs23;
        const float p01 = x01.x * x01.y;
        const float p23 = x23.x * x23.y;
        const float n01 = s01.x + s01.y;
        const float n23 = s23.x + s23.y;
        const float P   = p01 * p23;
        const float N   = fmaf(n01, p23, n23 * p01);
        acci = fmaf(N, __builtin_amdgcn_rcpf(P), acci);
      }
      acc[i] = acci;
    }
    #pragma unroll
    for (int i = 0; i < 8; i++){   // reduce over o8 group (lanes ^1,^2,^4)
      float a = acc[i];
      a = dpp_add<0xB1>(a);        // quad_perm xor1
      a = dpp_add<0x4E>(a);        // quad_perm xor2
      a = dpp_add<0x141>(a);       // row_half_mirror (xor4)
      acc[i] = a;
    }
    float sc = acc[0];
    #pragma unroll
    for (int i = 1; i < 8; i++) sc = (o8 == i) ? acc[i] : sc;
    sc8[kt] = sc;                  // PARTIAL score (h-half hh) key kt*64+o8*8+s8

    if (kt < 7)
      *(uint4*)(&tkb_s[(kt+1) & 1][sk*KBSTR + shh]) = st;
    __syncthreads();
  }

  // ======== combine h-halves + softmax (register key-order) ========
  float* psc = (float*)&tkb_s[0][0];   // tiles dead; 16KB spill scratch
  if (hh == 1){                    // spill hh=1 partials (key-indexed)
    #pragma unroll
    for (int kt = 0; kt < 8; kt++)
      psc[qr*TKN + kt*64 + o8*8 + s8] = sc8[kt];
  }
  __syncthreads();
  if (hh == 0){                    // wave qr: full softmax for its q-row
    float vals[8];
    float m = -1e30f;
    #pragma unroll
    for (int j = 0; j < 8; j++){
      vals[j] = sc8[j] + psc[qr*TKN + j*64 + o8*8 + s8];
      m = fmaxf(m, vals[j]);
    }
    #pragma unroll
    for (int o = 32; o > 0; o >>= 1) m = fmaxf(m, __shfl_xor(m, o));
    float sum = 0.f;
    #pragma unroll
    for (int j = 0; j < 8; j++){
      vals[j] = __builtin_amdgcn_exp2f((vals[j]-m)*1.4426950408889634f);
      sum += vals[j];
    }
    #pragma unroll
    for (int o = 32; o > 0; o >>= 1) sum += __shfl_xor(sum, o);
    const float inv = __builtin_amdgcn_rcpf(sum);
    // lane-transpose via bpermute -> coalesced stores
    const int psrc = ((((lane & 7) << 3) | (lane >> 3)) << 2);
    const size_t wbase = (size_t)NB*TQN*HD + (size_t)(b*TQN + qbase + qr)*TKN;
    float* wrow = wgt_s + qr*TKN;
    #pragma unroll
    for (int j = 0; j < 8; j++){
      union { float f; int i; } u; u.f = vals[j]*inv;
      union { int i; float f; } t; t.i = __builtin_amdgcn_ds_bpermute(psrc, u.i);
      wrow[j*64 + lane] = t.f;
      if (fQ) ((float*)out)[wbase + j*64 + lane] = t.f;
      else    ((unsigned short*)out)[wbase + j*64 + lane] = (unsigned short)f2bf(t.f);
    }
  }
  __syncthreads();

  // ======== phase 3: contexts = weights @ keys, DIRECT from L2 ========
  // p2 = wv&3 -> rows {2p2, 2p2+1}; g2 = wv>>2 -> key quarter [g2*128,+128).
  {
    const int p2 = wv & 3;
    const int g2 = wv >> 2;
    const int h0 = ln * 8;
    f32x2 a0v[4], a1v[4];
    #pragma unroll
    for (int t = 0; t < 4; t++){
      a0v[t].x = 0.f; a0v[t].y = 0.f;
      a1v[t].x = 0.f; a1v[t].y = 0.f;
    }
    const float* w0rb = wgt_s + (2*p2)*TKN;
    if (!fK){
      const unsigned short* kb = (const unsigned short*)keys
          + (size_t)(b*TKN)*HD + h0;
      #pragma unroll
      for (int t = 0; t < 2; t++){
        const int kt = g2*2 + t;
        const float* w0r = w0rb + kt*KTILE;
        const float* w1r = w0r + TKN;
        #pragma unroll
        for (int i = 0; i < 16; i++){
          const int k = i*4 + quad;
          const uint4 v = *(const uint4*)(kb + (size_t)(kt*KTILE + k)*HD);
          const float w0 = w0r[k];
          const float w1 = w1r[k];
          f32x2 c0; c0.x = lo16(v.x); c0.y = hi16(v.x);
          f32x2 c1; c1.x = lo16(v.y); c1.y = hi16(v.y);
          f32x2 c2; c2.x = lo16(v.z); c2.y = hi16(v.z);
          f32x2 c3; c3.x = lo16(v.w); c3.y = hi16(v.w);
          f32x2 w0v; w0v.x = w0; w0v.y = w0;
          f32x2 w1v; w1v.x = w1; w1v.y = w1;
          a0v[0] = FMA2(w0v, c0, a0v[0]); a0v[1] = FMA2(w0v, c1, a0v[1]);
          a0v[2] = FMA2(w0v, c2, a0v[2]); a0v[3] = FMA2(w0v, c3, a0v[3]);
          a1v[0] = FMA2(w1v, c0, a1v[0]); a1v[1] = FMA2(w1v, c1, a1v[1]);
          a1v[2] = FMA2(w1v, c2, a1v[2]); a1v[3] = FMA2(w1v, c3, a1v[3]);
        }
      }
    } else {
      const float* kb = (const float*)keys + (size_t)(b*TKN)*HD + h0;
      #pragma unroll
      for (int t = 0; t < 2; t++){
        const int kt = g2*2 + t;
        const float* w0r = w0rb + kt*KTILE;
        const float* w1r = w0r + TKN;
        #pragma unroll
        for (int i = 0; i < 16; i++){
          const int k = i*4 + quad;
          const float* kr = kb + (size_t)(kt*KTILE + k)*HD;
          const float4 k0 = *(const float4*)(kr);
          const float4 k1 = *(const float4*)(kr + 4);
          const float w0 = w0r[k];
          const float w1 = w1r[k];
          f32x2 c0; c0.x = k0.x; c0.y = k0.y;
          f32x2 c1; c1.x = k0.z; c1.y = k0.w;
          f32x2 c2; c2.x = k1.x; c2.y = k1.y;
          f32x2 c3; c3.x = k1.z; c3.y = k1.w;
          f32x2 w0v; w0v.x = w0; w0v.y = w0;
          f32x2 w1v; w1v.x = w1; w1v.y = w1;
          a0v[0] = FMA2(w0v, c0, a0v[0]); a0v[1] = FMA2(w0v, c1, a0v[1]);
          a0v[2] = FMA2(w0v, c2, a0v[2]); a0v[3] = FMA2(w0v, c3, a0v[3]);
          a1v[0] = FMA2(w1v, c0, a1v[0]); a1v[1] = FMA2(w1v, c1, a1v[1]);
          a1v[2] = FMA2(w1v, c2, a1v[2]); a1v[3] = FMA2(w1v, c3, a1v[3]);
        }
      }
    }
    float a0[8], a1[8];
    #pragma unroll
    for (int t = 0; t < 4; t++){
      a0[2*t] = a0v[t].x; a0[2*t+1] = a0v[t].y;
      a1[2*t] = a1v[t].x; a1[2*t+1] = a1v[t].y;
    }
    #pragma unroll
    for (int t = 0; t < 8; t++){
      a0[t] += __shfl_xor(a0[t], 16); a0[t] += __shfl_xor(a0[t], 32);
      a1[t] += __shfl_xor(a1[t], 16); a1[t] += __shfl_xor(a1[t], 32);
    }
    __syncthreads();                  // all waves done reading wgt_s
    float* part = psc;                // 16KB scratch (3072 floats used)
    if (g2 > 0 && quad == 0){
      const int base = ((g2-1)*8 + 2*p2)*HD + h0;
      *(float4*)(part + base       ) = (float4){a0[0],a0[1],a0[2],a0[3]};
      *(float4*)(part + base + 4   ) = (float4){a0[4],a0[5],a0[6],a0[7]};
      *(float4*)(part + base + HD  ) = (float4){a1[0],a1[1],a1[2],a1[3]};
      *(float4*)(part + base + HD+4) = (float4){a1[4],a1[5],a1[6],a1[7]};
    }
    __syncthreads();
    if (g2 == 0 && quad == 0){
      #pragma unroll
      for (int gg = 0; gg < 3; gg++){
        const int base = (gg*8 + 2*p2)*HD + h0;
        const float4 q00 = *(const float4*)(part + base);
        const float4 q01 = *(const float4*)(part + base + 4);
        const float4 q10 = *(const float4*)(part + base + HD);
        const float4 q11 = *(const float4*)(part + base + HD + 4);
        a0[0]+=q00.x; a0[1]+=q00.y; a0[2]+=q00.z; a0[3]+=q00.w;
        a0[4]+=q01.x; a0[5]+=q01.y; a0[6]+=q01.z; a0[7]+=q01.w;
        a1[0]+=q10.x; a1[1]+=q10.y; a1[2]+=q10.z; a1[3]+=q10.w;
        a1[4]+=q11.x; a1[5]+=q11.y; a1[6]+=q11.z; a1[7]+=q11.w;
      }
      const size_t crow0 = (size_t)(b*TQN + qbase + 2*p2    )*HD + h0;
      const size_t crow1 = (size_t)(b*TQN + qbase + 2*p2 + 1)*HD + h0;
      if (fQ){
        float* oc = (float*)out;
        *(float4*)(oc + crow0)     = (float4){a0[0],a0[1],a0[2],a0[3]};
        *(float4*)(oc + crow0 + 4) = (float4){a0[4],a0[5],a0[6],a0[7]};
        *(float4*)(oc + crow1)     = (float4){a1[0],a1[1],a1[2],a1[3]};
        *(float4*)(oc + crow1 + 4) = (float4){a1[4],a1[5],a1[6],a1[7]};
      } else {
        uint4 o0, o1;
        o0.x = f2bf(a0[0]) | (f2bf(a0[1]) << 16);
        o0.y = f2bf(a0[2]) | (f2bf(a0[3]) << 16);
        o0.z = f2bf(a0[4]) | (f2bf(a0[5]) << 16);
        o0.w = f2bf(a0[6]) | (f2bf(a0[7]) << 16);
        o1.x = f2bf(a1[0]) | (f2bf(a1[1]) << 16);
        o1.y = f2bf(a1[2]) | (f2bf(a1[3]) << 16);
        o1.z = f2bf(a1[4]) | (f2bf(a1[5]) << 16);
        o1.w = f2bf(a1[6]) | (f2bf(a1[7]) << 16);
        *(uint4*)((unsigned short*)out + crow0) = o0;
        *(uint4*)((unsigned short*)out + crow1) = o1;
      }
    }
  }
}

// ================= fallback: single kernel (passes @ ~101 us) =========
__global__ __launch_bounds__(512, 4) void fused_kernel(
    const void* __restrict__ queries, const void* __restrict__ keys,
    const void* __restrict__ Wa_w,   const void* __restrict__ Wa_b,
    const void* __restrict__ Ua_w,   const void* __restrict__ Ua_b,
    const void* __restrict__ Va_w,
    void* __restrict__ out)
{
  __shared__ float qp_s[FQT*QSTR];
  __shared__ float va_s[HD];
  __shared__ __align__(16) unsigned short keys_s[KTILE*KBSTR];
  __shared__ __align__(16) float kp_s[KTILE*KSTR];
  __shared__ float sc_s[FQT*TKN];
  __shared__ unsigned int flg_s[8];

  const int tid = threadIdx.x;
  if (tid < 8) flg_s[tid] = 0;
  __syncthreads();
  {
    const void* ptrs[7] = {queries, keys, Wa_w, Wa_b, Ua_w, Ua_b, Va_w};
    const int grp = tid >> 5;
    const int l   = tid & 31;
    if (grp < 7){
      const unsigned short* p = (const unsigned short*)ptrs[grp];
      unsigned short a = p[2*l], c = p[64 + 2*l];
      if (((a >> 7) & 0xFF) > 0x90 || ((c >> 7) & 0xFF) > 0x90)
        atomicOr(&flg_s[grp], 1u);
    }
  }
  __syncthreads();
  const bool fQ  = flg_s[0] != 0;
  const bool fK  = flg_s[1] != 0;
  const bool fWw = flg_s[2] != 0;
  const bool fWb = flg_s[3] != 0;
  const bool fUw = flg_s[4] != 0;
  const bool fUb = flg_s[5] != 0;
  const bool fVw = flg_s[6] != 0;

  const int lane = tid & 63;
  const int wv   = tid >> 6;
  const int ln   = lane & 15;
  const int quad = lane >> 4;
  const int b     = blockIdx.x >> 6;
  const int qbase = (blockIdx.x & 63) * FQT;

  if (tid < HD) va_s[tid] = ld1(Va_w, tid, fVw);
  {
    const int h0 = wv * 16;
    const size_t qrow = (size_t)(b*TQN + qbase + (ln & 7))*HD;
    f32x4 c = {0.f,0.f,0.f,0.f};
    #pragma unroll
    for (int ks = 0; ks < 4; ks++){
      short8 a = ld8bf(queries, qrow + ks*32 + quad*8, fQ);
      short8 w = ld8bf(Wa_w, (size_t)(h0 + ln)*HD + ks*32 + quad*8, fWw);
      c = __builtin_amdgcn_mfma_f32_16x16x32_bf16(a, w, c, 0,0,0);
    }
    const float wb = ld1(Wa_b, h0 + ln, fWb);
    #pragma unroll
    for (int r = 0; r < 4; r++){
      const int row = quad*4 + r;
      if (row < FQT) qp_s[row*QSTR + h0 + ln] = tanh_acc(c[r] + wb);
    }
  }
  short8 ub[4];
  float ubias;
  {
    const int h0 = wv * 16;
    #pragma unroll
    for (int ks = 0; ks < 4; ks++)
      ub[ks] = ld8bf(Ua_w, (size_t)(h0 + ln)*HD + ks*32 + quad*8, fUw);
    ubias = ld1(Ua_b, h0 + ln, fUb);
  }
  { // stage keys tile 0
    if (fK){
      const float4* src = (const float4*)((const float*)keys + (size_t)(b*TKN)*HD);
      #pragma unroll
      for (int j = 0; j < 4; j++){
        const int f = tid + 512*j;
        float4 v = src[f];
        const int k = f >> 5, h = (f & 31)*4;
        uint2 p;
        p.x = f2bf(v.x) | (f2bf(v.y) << 16);
        p.y = f2bf(v.z) | (f2bf(v.w) << 16);
        *(uint2*)(keys_s + k*KBSTR + h) = p;
      }
    } else {
      const uint4* src = (const uint4*)((const unsigned short*)keys + (size_t)(b*TKN)*HD);
      #pragma unroll
      for (int j = 0; j < 2; j++){
        const int f = tid + 512*j;
        uint4 v = src[f];
        const int k = f >> 4, h = (f & 15)*8;
        *(uint4*)(keys_s + k*KBSTR + h) = v;
      }
    }
  }
  __syncthreads();

  const int s8 = lane >> 3;
  const int o8 = lane & 7;
  float tqr[16], var[16], vat[16];
  {
    const float* qsrc = qp_s + wv*QSTR + o8*16;
    const float* vsrc = va_s + o8*16;
    #pragma unroll
    for (int c = 0; c < 4; c++){
      float4 t = *(const float4*)(qsrc + c*4);
      float4 v = *(const float4*)(vsrc + c*4);
      tqr[c*4+0]=t.x; tqr[c*4+1]=t.y; tqr[c*4+2]=t.z; tqr[c*4+3]=t.w;
      var[c*4+0]=v.x; var[c*4+1]=v.y; var[c*4+2]=v.z; var[c*4+3]=v.w;
      vat[c*4+0]=v.x*t.x; vat[c*4+1]=v.y*t.y; vat[c*4+2]=v.z*t.z; vat[c*4+3]=v.w*t.w;
    }
  }
  for (int kt = 0; kt < 8; kt++){
    f32x4 kc[4];
    #pragma unroll
    for (int mt = 0; mt < 4; mt++) kc[mt] = (f32x4){0.f,0.f,0.f,0.f};
    #pragma unroll
    for (int ks = 0; ks < 4; ks++){
      short8 af[4];
      #pragma unroll
      for (int mt = 0; mt < 4; mt++)
        af[mt] = *(const short8*)(keys_s + (mt*16 + ln)*KBSTR + ks*32 + quad*8);
      #pragma unroll
      for (int mt = 0; mt < 4; mt++)
        kc[mt] = __builtin_amdgcn_mfma_f32_16x16x32_bf16(af[mt], ub[ks], kc[mt], 0,0,0);
    }
    __syncthreads();
    #pragma unroll
    for (int mt = 0; mt < 4; mt++)
      #pragma unroll
      for (int r = 0; r < 4; r++)
        kp_s[(mt*16 + quad*4 + r)*KSTR + wv*16 + ln] = tanh_acc(kc[mt][r] + ubias);
    if (kt < 7){
      if (fK){
        const float4* src = (const float4*)((const float*)keys + (size_t)(b*TKN + (kt+1)*KTILE)*HD);
        #pragma unroll
        for (int j = 0; j < 4; j++){
          const int f = tid + 512*j;
          float4 v = src[f];
          const int k = f >> 5, h = (f & 31)*4;
          uint2 p;
          p.x = f2bf(v.x) | (f2bf(v.y) << 16);
          p.y = f2bf(v.z) | (f2bf(v.w) << 16);
          *(uint2*)(keys_s + k*KBSTR + h) = p;
        }
      } else {
        const uint4* src = (const uint4*)((const unsigned short*)keys + (size_t)(b*TKN + (kt+1)*KTILE)*HD);
        #pragma unroll
        for (int j = 0; j < 2; j++){
          const int f = tid + 512*j;
          uint4 v = src[f];
          const int k = f >> 4, h = (f & 15)*8;
          *(uint4*)(keys_s + k*KBSTR + h) = v;
        }
      }
    }
    __syncthreads();
    float acc[8];
    #pragma unroll
    for (int i = 0; i < 8; i++) acc[i] = 0.f;
    #pragma unroll
    for (int i = 0; i < 8; i++){
      const float* tk = kp_s + (i*8 + s8)*KSTR + o8*16;
      #pragma unroll
      for (int c = 0; c < 4; c++){
        const float4 kv = *(const float4*)(tk + c*4);
        acc[i] = fmaf(fmaf(var[c*4+0], kv.x, vat[c*4+0]),
                      __builtin_amdgcn_rcpf(fmaf(tqr[c*4+0], kv.x, 1.f)), acc[i]);
        acc[i] = fmaf(fmaf(var[c*4+1], kv.y, vat[c*4+1]),
                      __builtin_amdgcn_rcpf(fmaf(tqr[c*4+1], kv.y, 1.f)), acc[i]);
        acc[i] = fmaf(fmaf(var[c*4+2], kv.z, vat[c*4+2]),
                      __builtin_amdgcn_rcpf(fmaf(tqr[c*4+2], kv.z, 1.f)), acc[i]);
        acc[i] = fmaf(fmaf(var[c*4+3], kv.w, vat[c*4+3]),
                      __builtin_amdgcn_rcpf(fmaf(tqr[c*4+3], kv.w, 1.f)), acc[i]);
      }
    }
    #pragma unroll
    for (int i = 0; i < 8; i++){
      float a = acc[i];
      a = dpp_add<0xB1>(a);
      a = dpp_add<0x4E>(a);
      a = dpp_add<0x141>(a);
      acc[i] = a;
    }
    float sc = acc[0];
    #pragma unroll
    for (int i = 1; i < 8; i++) sc = (o8 == i) ? acc[i] : sc;
    sc_s[wv*TKN + kt*KTILE + o8*8 + s8] = sc;
  }
  __syncthreads();
  {
    float vals[8];
    float m = -1e30f;
    #pragma unroll
    for (int j = 0; j < 8; j++){
      vals[j] = sc_s[wv*TKN + lane + 64*j];
      m = fmaxf(m, vals[j]);
    }
    #pragma unroll
    for (int o = 32; o > 0; o >>= 1) m = fmaxf(m, __shfl_xor(m, o));
    float sum = 0.f;
    #pragma unroll
    for (int j = 0; j < 8; j++){
      vals[j] = __builtin_amdgcn_exp2f((vals[j]-m)*1.4426950408889634f);
      sum += vals[j];
    }
    #pragma unroll
    for (int o = 32; o > 0; o >>= 1) sum += __shfl_xor(sum, o);
    const float inv = __builtin_amdgcn_rcpf(sum);
    const size_t wbase = (size_t)NB*TQN*HD + (size_t)(b*TQN + qbase + wv)*TKN;
    #pragma unroll
    for (int j = 0; j < 8; j++){
      const float w = vals[j]*inv;
      sc_s[wv*TKN + lane + 64*j] = w;
      if (fQ) ((float*)out)[wbase + lane + 64*j] = w;
      else    ((unsigned short*)out)[wbase + lane + 64*j] = (unsigned short)f2bf(w);
    }
  }
  __syncthreads();
  {
    const int p2 = wv & 3;
    const int g2 = wv >> 2;
    const int h0 = ln * 8;
    float a0[8], a1[8];
    #pragma unroll
    for (int t = 0; t < 8; t++){ a0[t] = 0.f; a1[t] = 0.f; }
    for (int kt = 0; kt < 8; kt++){
      if (fK){
        const float4* src = (const float4*)((const float*)keys + (size_t)(b*TKN + kt*KTILE)*HD);
        #pragma unroll
        for (int j = 0; j < 4; j++){
          const int f = tid + 512*j;
          const int k = f >> 5, h = (f & 31)*4;
          *(float4*)(kp_s + k*KSTR + h) = src[f];
        }
      } else {
        const uint4* src = (const uint4*)((const unsigned short*)keys + (size_t)(b*TKN + kt*KTILE)*HD);
        #pragma unroll
        for (int j = 0; j < 2; j++){
          const int f = tid + 512*j;
          const int k = f >> 4, h = (f & 15)*8;
          uint4 v = src[f];
          float4 d0, d1;
          d0.x = lo16(v.x); d0.y = hi16(v.x); d0.z = lo16(v.y); d0.w = hi16(v.y);
          d1.x = lo16(v.z); d1.y = hi16(v.z); d1.z = lo16(v.w); d1.w = hi16(v.w);
          *(float4*)(kp_s + k*KSTR + h)     = d0;
          *(float4*)(kp_s + k*KSTR + h + 4) = d1;
        }
      }
      __syncthreads();
      const float* w0r = sc_s + (2*p2)*TKN + kt*KTILE + g2*32;
      const float* w1r = w0r + TKN;
      #pragma unroll
      for (int i = 0; i < 8; i++){
        const int k = i*4 + quad;
        const float w0 = w0r[k];
        const float w1 = w1r[k];
        const float* kr = kp_s + (g2*32 + k)*KSTR + h0;
        const float4 k0 = *(const float4*)(kr);
        const float4 k1 = *(const float4*)(kr + 4);
        a0[0]=fmaf(w0,k0.x,a0[0]); a0[1]=fmaf(w0,k0.y,a0[1]);
        a0[2]=fmaf(w0,k0.z,a0[2]); a0[3]=fmaf(w0,k0.w,a0[3]);
        a0[4]=fmaf(w0,k1.x,a0[4]); a0[5]=fmaf(w0,k1.y,a0[5]);
        a0[6]=fmaf(w0,k1.z,a0[6]); a0[7]=fmaf(w0,k1.w,a0[7]);
        a1[0]=fmaf(w1,k0.x,a1[0]); a1[1]=fmaf(w1,k0.y,a1[1]);
        a1[2]=fmaf(w1,k0.z,a1[2]); a1[3]=fmaf(w1,k0.w,a1[3]);
        a1[4]=fmaf(w1,k1.x,a1[4]); a1[5]=fmaf(w1,k1.y,a1[5]);
        a1[6]=fmaf(w1,k1.z,a1[6]); a1[7]=fmaf(w1,k1.w,a1[7]);
      }
      __syncthreads();
    }
    #pragma unroll
    for (int t = 0; t < 8; t++){
      a0[t] += __shfl_xor(a0[t], 16); a0[t] += __shfl_xor(a0[t], 32);
      a1[t] += __shfl_xor(a1[t], 16); a1[t] += __shfl_xor(a1[t], 32);
    }
    float* part = qp_s;
    if (g2 == 1 && quad == 0){
      *(float4*)(part + (2*p2  )*HD + h0    ) = (float4){a0[0],a0[1],a0[2],a0[3]};
      *(float4*)(part + (2*p2  )*HD + h0 + 4) = (float4){a0[4],a0[5],a0[6],a0[7]};
      *(float4*)(part + (2*p2+1)*HD + h0    ) = (float4){a1[0],a1[1],a1[2],a1[3]};
      *(float4*)(part + (2*p2+1)*HD + h0 + 4) = (float4){a1[4],a1[5],a1[6],a1[7]};
    }
    __syncthreads();
    if (g2 == 0 && quad == 0){
      const float4 p00 = *(const float4*)(part + (2*p2  )*HD + h0    );
      const float4 p01 = *(const float4*)(part + (2*p2  )*HD + h0 + 4);
      const float4 p10 = *(const float4*)(part + (2*p2+1)*HD + h0    );
      const float4 p11 = *(const float4*)(part + (2*p2+1)*HD + h0 + 4);
      const size_t crow0 = (size_t)(b*TQN + qbase + 2*p2    )*HD + h0;
      const size_t crow1 = (size_t)(b*TQN + qbase + 2*p2 + 1)*HD + h0;
      if (fQ){
        float* oc = (float*)out;
        *(float4*)(oc + crow0)     = (float4){a0[0]+p00.x, a0[1]+p00.y, a0[2]+p00.z, a0[3]+p00.w};
        *(float4*)(oc + crow0 + 4) = (float4){a0[4]+p01.x, a0[5]+p01.y, a0[6]+p01.z, a0[7]+p01.w};
        *(float4*)(oc + crow1)     = (float4){a1[0]+p10.x, a1[1]+p10.y, a1[2]+p10.z, a1[3]+p10.w};
        *(float4*)(oc + crow1 + 4) = (float4){a1[4]+p11.x, a1[5]+p11.y, a1[6]+p11.z, a1[7]+p11.w};
      } else {
        uint4 o0, o1;
        o0.x = f2bf(a0[0]+p00.x) | (f2bf(a0[1]+p00.y) << 16);
        o0.y = f2bf(a0[2]+p00.z) | (f2bf(a0[3]+p00.w) << 16);
        o0.z = f2bf(a0[4]+p01.x) | (f2bf(a0[5]+p01.y) << 16);
        o0.w = f2bf(a0[6]+p01.z) | (f2bf(a0[7]+p01.w) << 16);
        o1.x = f2bf(a1[0]+p10.x) | (f2bf(a1[1]+p10.y) << 16);
        o1.y = f2bf(a1[2]+p10.z) | (f2bf(a1[3]+p10.w) << 16);
        o1.z = f2bf(a1[4]+p11.x) | (f2bf(a1[5]+p11.y) << 16);
        o1.w = f2bf(a1[6]+p11.z) | (f2bf(a1[7]+p11.w) << 16);
        *(uint4*)((unsigned short*)out + crow0) = o0;
        *(uint4*)((unsigned short*)out + crow1) = o1;
      }
    }
  }
}

extern "C" void kernel_launch(void* const* d_in, const int* in_sizes, int n_in,
                              void* d_out, int out_size, void* d_ws, size_t ws_size,
                              hipStream_t stream) {
  (void)in_sizes; (void)n_in; (void)out_size;
  const size_t need = (size_t)NB * TKN * HD * sizeof(unsigned short) * 2;  // 2 MB guard
  if (ws_size >= need){
    unsigned short* tk_gb = (unsigned short*)d_ws;
    kproj_kernel<<<256, 256, 0, stream>>>(d_in[1], d_in[4], d_in[5], tk_gb);
    attn_kernel<<<512, 1024, 0, stream>>>(d_in[0], d_in[1], d_in[2], d_in[3],
                                          d_in[6], tk_gb, d_out);
  } else {
    fused_kernel<<<512, 512, 0, stream>>>(d_in[0], d_in[1], d_in[2], d_in[3],
                                          d_in[4], d_in[5], d_in[6], d_out);
  }
}

// Round 10
// 136.542 us; speedup vs baseline: 1.4904x; 1.0527x over previous
//
#include <hip/hip_runtime.h>
#include <hip/hip_bf16.h>
#include <stdint.h>

#define HD 128
#define NB 8
#define TQN 512
#define TKN 512
#define QT 8        // queries per block (K2)
#define KTILE 64
#define KSTR 132    // f32 stride (fallback kp_s)
#define QSTR 132
#define KBSTR 136   // bf16 tile row stride (ushorts): rows 16B-aligned
#define FQT 8       // fallback queries per block

typedef __attribute__((ext_vector_type(8))) short short8;  // 8 bf16
typedef __attribute__((ext_vector_type(4))) float f32x4;   // MFMA C/D
typedef __attribute__((ext_vector_type(2))) float f32x2;   // packed-f32 pair

#if __has_builtin(__builtin_elementwise_fma)
#define FMA2(a,b,c) __builtin_elementwise_fma((a),(b),(c))
#else
#define FMA2(a,b,c) ((a)*(b)+(c))
#endif

static __device__ __forceinline__ float lo16(uint32_t w){
  union { uint32_t i; float f; } v; v.i = w << 16; return v.f;
}
static __device__ __forceinline__ float hi16(uint32_t w){
  union { uint32_t i; float f; } v; v.i = w & 0xffff0000u; return v.f;
}
static __device__ __forceinline__ float bf2f(unsigned short u){
  union { uint32_t i; float f; } v; v.i = ((uint32_t)u) << 16; return v.f;
}
static __device__ __forceinline__ uint32_t f2bf(float f){   // RNE
  union { float f; uint32_t i; } v; v.f = f;
  uint32_t u = v.i;
  u += 0x7fffu + ((u >> 16) & 1u);
  return u >> 16;
}
static __device__ __forceinline__ float tanh_acc(float x){
  float e = __builtin_amdgcn_exp2f(x * 2.8853900817779268f);
  return fmaf(-2.0f, __builtin_amdgcn_rcpf(e + 1.0f), 1.0f);
}
template<int CTRL>
static __device__ __forceinline__ float dpp_add(float x){
  union { float f; int i; } u; u.f = x;
  int y = __builtin_amdgcn_update_dpp(0, u.i, CTRL, 0xf, 0xf, true);
  union { int i; float f; } w; w.i = y;
  return x + w.f;
}
static __device__ __forceinline__ float ld1(const void* p, size_t idx, bool f32){
  return f32 ? ((const float*)p)[idx] : bf2f(((const unsigned short*)p)[idx]);
}
static __device__ __forceinline__ short8 ld8bf(const void* p, size_t idx, bool f32){
  short8 r;
  if (f32){
    const float* s = (const float*)p + idx;
    #pragma unroll
    for (int i = 0; i < 8; i++) r[i] = (short)f2bf(s[i]);
  } else {
    r = *(const short8*)((const unsigned short*)p + idx);
  }
  return r;
}

// ================= K1: projection + exp precompute (R7 + tq bf16) ========
// Stores E = clamp(exp(2*(x@W.T+b)), 2^-13, 2^13) as BF16 for BOTH tq and
// tk (R7 had tq f32; bf16 halves proj's write traffic 10.5->4.2MB).
// va*tanh(q+k) = va - 2*va/(Eq*Ek+1); constant sum(va)+Vb dropped in K2.
__global__ __launch_bounds__(256) void proj_kernel(
    const void* __restrict__ queries, const void* __restrict__ keys,
    const void* __restrict__ Wa_w,   const void* __restrict__ Wa_b,
    const void* __restrict__ Ua_w,   const void* __restrict__ Ua_b,
    unsigned short* __restrict__ tq_gb, unsigned short* __restrict__ tk_gb)
{
  __shared__ unsigned int flg_s[8];
  const int tid = threadIdx.x;
  if (tid < 8) flg_s[tid] = 0;
  __syncthreads();
  {
    const void* ptrs[6] = {queries, keys, Wa_w, Wa_b, Ua_w, Ua_b};
    const int grp = tid >> 5;
    const int l   = tid & 31;
    if (grp < 6){
      const unsigned short* p = (const unsigned short*)ptrs[grp];
      unsigned short a = p[2*l], c = p[64 + 2*l];
      if (((a >> 7) & 0xFF) > 0x90 || ((c >> 7) & 0xFF) > 0x90)
        atomicOr(&flg_s[grp], 1u);
    }
  }
  __syncthreads();
  const int lane = tid & 63, wv = tid >> 6, ln = lane & 15, quad = lane >> 4;
  // XCD-batch affinity matching attn_kernel's b=blockIdx&7.
  const int b7  = blockIdx.x & 7;
  const int idx = blockIdx.x >> 3;   // 0..63
  const int row0 = (idx < 32) ? (b7*TQN + idx*16)
                              : (NB*TQN + b7*TKN + (idx-32)*16);

  const void* x; const void* W; const void* bias; unsigned short* dst; int r;
  bool fx, fw, fb;
  if (row0 < NB*TQN){
    x = queries; W = Wa_w; bias = Wa_b; dst = tq_gb; r = row0;
    fx = flg_s[0] != 0; fw = flg_s[2] != 0; fb = flg_s[3] != 0;
  } else {
    x = keys; W = Ua_w; bias = Ua_b; dst = tk_gb; r = row0 - NB*TQN;
    fx = flg_s[1] != 0; fw = flg_s[4] != 0; fb = flg_s[5] != 0;
  }

  short8 a[4];
  #pragma unroll
  for (int ks = 0; ks < 4; ks++)
    a[ks] = ld8bf(x, (size_t)(r + ln)*HD + ks*32 + quad*8, fx);

  #pragma unroll
  for (int nt = 0; nt < 2; nt++){
    const int h0 = (2*wv + nt)*16;
    f32x4 c = {0.f,0.f,0.f,0.f};
    #pragma unroll
    for (int ks = 0; ks < 4; ks++)
      c = __builtin_amdgcn_mfma_f32_16x16x32_bf16(
            a[ks], ld8bf(W, (size_t)(h0 + ln)*HD + ks*32 + quad*8, fw), c, 0,0,0);
    const float wb = ld1(bias, h0 + ln, fb);
    #pragma unroll
    for (int r4 = 0; r4 < 4; r4++){  // D: col=ln, row=quad*4+r4
      const float e = __builtin_amdgcn_exp2f((c[r4] + wb) * 2.8853900817779268f);
      dst[(size_t)(r + quad*4 + r4)*HD + h0 + ln] =
          (unsigned short)f2bf(fminf(fmaxf(e, 0x1p-13f), 0x1p13f));
    }
  }
}

// ================= K2: scores + softmax + contexts (R7 structure) ========
// Double-buffered bf16 tiles, ONE barrier per tile:
// { issue loads(kt+1); compute buf[kt&1]; write buf[(kt+1)&1]; barrier }.
// QT=8, grid 512, 1024 threads = 16 waves (qr=wv&7, hh=wv>>3);
// LDS = 2*17KB tiles + 16KB wgt ~ 51KB -> 2 blocks/CU, 32 waves/CU.
__global__ __launch_bounds__(1024, 8) void attn_kernel(
    const void* __restrict__ queries, const void* __restrict__ keys,
    const void* __restrict__ Va_w,
    const unsigned short* __restrict__ tq_gb,
    const unsigned short* __restrict__ tk_gb,
    void* __restrict__ out)
{
  __shared__ __align__(16) unsigned short tkb_s[2][KTILE*KBSTR]; // 2x17408B
  __shared__ float wgt_s[QT*TKN];                                // 16 KB
  __shared__ unsigned int flg_s[4];

  const int tid = threadIdx.x;
  // XCD-batch affinity: batch = blockIdx&7 (64 blocks/batch on one XCD L2).
  const int b     = blockIdx.x & 7;
  const int qbase = (blockIdx.x >> 3) * QT;

  // tile-0 prefetch before flag check (hides latency); one uint4 = 8 bf16
  uint4 st;
  {
    const uint4* src = (const uint4*)(tk_gb + (size_t)(b*TKN)*HD);
    st = src[tid];   // row=tid>>4, h=(tid&15)*8
  }

  if (tid < 4) flg_s[tid] = 0;
  __syncthreads();
  {
    const void* ptrs[3] = {queries, keys, Va_w};
    const int grp = tid >> 5;
    const int l   = tid & 31;
    if (grp < 3){
      const unsigned short* p = (const unsigned short*)ptrs[grp];
      unsigned short a = p[2*l], c = p[64 + 2*l];
      if (((a >> 7) & 0xFF) > 0x90 || ((c >> 7) & 0xFF) > 0x90)
        atomicOr(&flg_s[grp], 1u);
    }
  }
  __syncthreads();
  const bool fQ  = flg_s[0] != 0;   // selects OUTPUT dtype
  const bool fK  = flg_s[1] != 0;
  const bool fVw = flg_s[2] != 0;

  const int lane = tid & 63;
  const int wv   = tid >> 6;        // wave id 0..15
  const int qr   = wv & 7;          // q-row within block
  const int hh   = wv >> 3;         // h-half 0/1 (within each octant)
  const int ln   = lane & 15;
  const int quad = lane >> 4;
  const int s8   = lane >> 3;       // key-slot 0..7
  const int o8   = lane & 7;        // h-octant
  const int sk   = tid >> 4;        // staging key row
  const int shh  = (tid & 15) * 8;  // staging h start

  // per-lane hoists: 8 floats, h = o8*16 + hh*8 + [0,8)  (Eq now bf16)
  f32x2 eq2[4], a2[4];
  {
    const unsigned short* qsrc =
        tq_gb + (size_t)(b*TQN + qbase + qr)*HD + o8*16 + hh*8;
    const uint4 qv = *(const uint4*)qsrc;
    eq2[0].x = lo16(qv.x); eq2[0].y = hi16(qv.x);
    eq2[1].x = lo16(qv.y); eq2[1].y = hi16(qv.y);
    eq2[2].x = lo16(qv.z); eq2[2].y = hi16(qv.z);
    eq2[3].x = lo16(qv.w); eq2[3].y = hi16(qv.w);
    #pragma unroll
    for (int c = 0; c < 4; c++){
      a2[c].x = -2.0f * ld1(Va_w, o8*16 + hh*8 + c*2 + 0, fVw);
      a2[c].y = -2.0f * ld1(Va_w, o8*16 + hh*8 + c*2 + 1, fVw);
    }
  }
  f32x2 one2; one2.x = 1.f; one2.y = 1.f;

  // ======== phase 1: double-buffered, 1 barrier/tile ========
  // write tile 0 -> buf0
  *(uint4*)(&tkb_s[0][sk*KBSTR + shh]) = st;
  __syncthreads();

  float sc8[8];
  for (int kt = 0; kt < 8; kt++){
    if (kt < 7){
      const uint4* src = (const uint4*)(tk_gb + (size_t)(b*TKN + (kt+1)*KTILE)*HD);
      st = src[tid];
    }
    const unsigned short* buf = &tkb_s[kt & 1][0];

    float acc[8];
    #pragma unroll
    for (int i = 0; i < 8; i++){
      const unsigned short* tk = buf + (i*8 + s8)*KBSTR + o8*16 + hh*8;
      const uint4 v = *(const uint4*)tk;
      float acci = 0.f;
      {  // quad 0: elements 0..3 (v.x, v.y)
        f32x2 kv0; kv0.x = lo16(v.x); kv0.y = hi16(v.x);
        f32x2 kv1; kv1.x = lo16(v.y); kv1.y = hi16(v.y);
        f32x2 x01 = FMA2(eq2[0], kv0, one2);
        f32x2 x23 = FMA2(eq2[1], kv1, one2);
        f32x2 xs01; xs01.x = x01.y; xs01.y = x01.x;
        f32x2 xs23; xs23.x = x23.y; xs23.y = x23.x;
        f32x2 s01 = a2[0] * xs01;
        f32x2 s23 = a2[1] * xs23;
        const float p01 = x01.x * x01.y;
        const float p23 = x23.x * x23.y;
        const float n01 = s01.x + s01.y;
        const float n23 = s23.x + s23.y;
        const float P   = p01 * p23;
        const float N   = fmaf(n01, p23, n23 * p01);
        acci = fmaf(N, __builtin_amdgcn_rcpf(P), acci);
      }
      {  // quad 1: elements 4..7 (v.z, v.w)
        f32x2 kv0; kv0.x = lo16(v.z); kv0.y = hi16(v.z);
        f32x2 kv1; kv1.x = lo16(v.w); kv1.y = hi16(v.w);
        f32x2 x01 = FMA2(eq2[2], kv0, one2);
        f32x2 x23 = FMA2(eq2[3], kv1, one2);
        f32x2 xs01; xs01.x = x01.y; xs01.y = x01.x;
        f32x2 xs23; xs23.x = x23.y; xs23.y = x23.x;
        f32x2 s01 = a2[2] * xs01;
        f32x2 s23 = a2[3] * xs23;
        const float p01 = x01.x * x01.y;
        const float p23 = x23.x * x23.y;
        const float n01 = s01.x + s01.y;
        const float n23 = s23.x + s23.y;
        const float P   = p01 * p23;
        const float N   = fmaf(n01, p23, n23 * p01);
        acci = fmaf(N, __builtin_amdgcn_rcpf(P), acci);
      }
      acc[i] = acci;
    }
    #pragma unroll
    for (int i = 0; i < 8; i++){   // reduce over o8 group (lanes ^1,^2,^4)
      float a = acc[i];
      a = dpp_add<0xB1>(a);        // quad_perm xor1
      a = dpp_add<0x4E>(a);        // quad_perm xor2
      a = dpp_add<0x141>(a);       // row_half_mirror (xor4)
      acc[i] = a;
    }
    float sc = acc[0];
    #pragma unroll
    for (int i = 1; i < 8; i++) sc = (o8 == i) ? acc[i] : sc;
    sc8[kt] = sc;                  // PARTIAL score (h-half hh) key kt*64+o8*8+s8

    if (kt < 7)
      *(uint4*)(&tkb_s[(kt+1) & 1][sk*KBSTR + shh]) = st;
    __syncthreads();
  }

  // ======== combine h-halves + softmax (register key-order) ========
  float* psc = (float*)&tkb_s[0][0];   // tiles dead; 16KB spill scratch
  if (hh == 1){                    // spill hh=1 partials (key-indexed)
    #pragma unroll
    for (int kt = 0; kt < 8; kt++)
      psc[qr*TKN + kt*64 + o8*8 + s8] = sc8[kt];
  }
  __syncthreads();
  if (hh == 0){                    // wave qr: full softmax for its q-row
    float vals[8];
    float m = -1e30f;
    #pragma unroll
    for (int j = 0; j < 8; j++){
      vals[j] = sc8[j] + psc[qr*TKN + j*64 + o8*8 + s8];
      m = fmaxf(m, vals[j]);
    }
    #pragma unroll
    for (int o = 32; o > 0; o >>= 1) m = fmaxf(m, __shfl_xor(m, o));
    float sum = 0.f;
    #pragma unroll
    for (int j = 0; j < 8; j++){
      vals[j] = __builtin_amdgcn_exp2f((vals[j]-m)*1.4426950408889634f);
      sum += vals[j];
    }
    #pragma unroll
    for (int o = 32; o > 0; o >>= 1) sum += __shfl_xor(sum, o);
    const float inv = __builtin_amdgcn_rcpf(sum);
    // lane-transpose via bpermute -> coalesced stores
    const int psrc = ((((lane & 7) << 3) | (lane >> 3)) << 2);
    const size_t wbase = (size_t)NB*TQN*HD + (size_t)(b*TQN + qbase + qr)*TKN;
    float* wrow = wgt_s + qr*TKN;
    #pragma unroll
    for (int j = 0; j < 8; j++){
      union { float f; int i; } u; u.f = vals[j]*inv;
      union { int i; float f; } t; t.i = __builtin_amdgcn_ds_bpermute(psrc, u.i);
      wrow[j*64 + lane] = t.f;
      if (fQ) ((float*)out)[wbase + j*64 + lane] = t.f;
      else    ((unsigned short*)out)[wbase + j*64 + lane] = (unsigned short)f2bf(t.f);
    }
  }
  __syncthreads();

  // ======== phase 3: contexts = weights @ keys, DIRECT from L2 ========
  // p2 = wv&3 -> rows {2p2, 2p2+1}; g2 = wv>>2 -> key quarter [g2*128,+128).
  {
    const int p2 = wv & 3;
    const int g2 = wv >> 2;
    const int h0 = ln * 8;
    f32x2 a0v[4], a1v[4];
    #pragma unroll
    for (int t = 0; t < 4; t++){
      a0v[t].x = 0.f; a0v[t].y = 0.f;
      a1v[t].x = 0.f; a1v[t].y = 0.f;
    }
    const float* w0rb = wgt_s + (2*p2)*TKN;
    if (!fK){
      const unsigned short* kb = (const unsigned short*)keys
          + (size_t)(b*TKN)*HD + h0;
      #pragma unroll
      for (int t = 0; t < 2; t++){
        const int kt = g2*2 + t;
        const float* w0r = w0rb + kt*KTILE;
        const float* w1r = w0r + TKN;
        #pragma unroll
        for (int i = 0; i < 16; i++){
          const int k = i*4 + quad;
          const uint4 v = *(const uint4*)(kb + (size_t)(kt*KTILE + k)*HD);
          const float w0 = w0r[k];
          const float w1 = w1r[k];
          f32x2 c0; c0.x = lo16(v.x); c0.y = hi16(v.x);
          f32x2 c1; c1.x = lo16(v.y); c1.y = hi16(v.y);
          f32x2 c2; c2.x = lo16(v.z); c2.y = hi16(v.z);
          f32x2 c3; c3.x = lo16(v.w); c3.y = hi16(v.w);
          f32x2 w0v; w0v.x = w0; w0v.y = w0;
          f32x2 w1v; w1v.x = w1; w1v.y = w1;
          a0v[0] = FMA2(w0v, c0, a0v[0]); a0v[1] = FMA2(w0v, c1, a0v[1]);
          a0v[2] = FMA2(w0v, c2, a0v[2]); a0v[3] = FMA2(w0v, c3, a0v[3]);
          a1v[0] = FMA2(w1v, c0, a1v[0]); a1v[1] = FMA2(w1v, c1, a1v[1]);
          a1v[2] = FMA2(w1v, c2, a1v[2]); a1v[3] = FMA2(w1v, c3, a1v[3]);
        }
      }
    } else {
      const float* kb = (const float*)keys + (size_t)(b*TKN)*HD + h0;
      #pragma unroll
      for (int t = 0; t < 2; t++){
        const int kt = g2*2 + t;
        const float* w0r = w0rb + kt*KTILE;
        const float* w1r = w0r + TKN;
        #pragma unroll
        for (int i = 0; i < 16; i++){
          const int k = i*4 + quad;
          const float* kr = kb + (size_t)(kt*KTILE + k)*HD;
          const float4 k0 = *(const float4*)(kr);
          const float4 k1 = *(const float4*)(kr + 4);
          const float w0 = w0r[k];
          const float w1 = w1r[k];
          f32x2 c0; c0.x = k0.x; c0.y = k0.y;
          f32x2 c1; c1.x = k0.z; c1.y = k0.w;
          f32x2 c2; c2.x = k1.x; c2.y = k1.y;
          f32x2 c3; c3.x = k1.z; c3.y = k1.w;
          f32x2 w0v; w0v.x = w0; w0v.y = w0;
          f32x2 w1v; w1v.x = w1; w1v.y = w1;
          a0v[0] = FMA2(w0v, c0, a0v[0]); a0v[1] = FMA2(w0v, c1, a0v[1]);
          a0v[2] = FMA2(w0v, c2, a0v[2]); a0v[3] = FMA2(w0v, c3, a0v[3]);
          a1v[0] = FMA2(w1v, c0, a1v[0]); a1v[1] = FMA2(w1v, c1, a1v[1]);
          a1v[2] = FMA2(w1v, c2, a1v[2]); a1v[3] = FMA2(w1v, c3, a1v[3]);
        }
      }
    }
    float a0[8], a1[8];
    #pragma unroll
    for (int t = 0; t < 4; t++){
      a0[2*t] = a0v[t].x; a0[2*t+1] = a0v[t].y;
      a1[2*t] = a1v[t].x; a1[2*t+1] = a1v[t].y;
    }
    #pragma unroll
    for (int t = 0; t < 8; t++){
      a0[t] += __shfl_xor(a0[t], 16); a0[t] += __shfl_xor(a0[t], 32);
      a1[t] += __shfl_xor(a1[t], 16); a1[t] += __shfl_xor(a1[t], 32);
    }
    __syncthreads();                  // all waves done reading wgt_s
    float* part = psc;                // 16KB scratch (3072 floats used)
    if (g2 > 0 && quad == 0){
      const int base = ((g2-1)*8 + 2*p2)*HD + h0;
      *(float4*)(part + base       ) = (float4){a0[0],a0[1],a0[2],a0[3]};
      *(float4*)(part + base + 4   ) = (float4){a0[4],a0[5],a0[6],a0[7]};
      *(float4*)(part + base + HD  ) = (float4){a1[0],a1[1],a1[2],a1[3]};
      *(float4*)(part + base + HD+4) = (float4){a1[4],a1[5],a1[6],a1[7]};
    }
    __syncthreads();
    if (g2 == 0 && quad == 0){
      #pragma unroll
      for (int gg = 0; gg < 3; gg++){
        const int base = (gg*8 + 2*p2)*HD + h0;
        const float4 q00 = *(const float4*)(part + base);
        const float4 q01 = *(const float4*)(part + base + 4);
        const float4 q10 = *(const float4*)(part + base + HD);
        const float4 q11 = *(const float4*)(part + base + HD + 4);
        a0[0]+=q00.x; a0[1]+=q00.y; a0[2]+=q00.z; a0[3]+=q00.w;
        a0[4]+=q01.x; a0[5]+=q01.y; a0[6]+=q01.z; a0[7]+=q01.w;
        a1[0]+=q10.x; a1[1]+=q10.y; a1[2]+=q10.z; a1[3]+=q10.w;
        a1[4]+=q11.x; a1[5]+=q11.y; a1[6]+=q11.z; a1[7]+=q11.w;
      }
      const size_t crow0 = (size_t)(b*TQN + qbase + 2*p2    )*HD + h0;
      const size_t crow1 = (size_t)(b*TQN + qbase + 2*p2 + 1)*HD + h0;
      if (fQ){
        float* oc = (float*)out;
        *(float4*)(oc + crow0)     = (float4){a0[0],a0[1],a0[2],a0[3]};
        *(float4*)(oc + crow0 + 4) = (float4){a0[4],a0[5],a0[6],a0[7]};
        *(float4*)(oc + crow1)     = (float4){a1[0],a1[1],a1[2],a1[3]};
        *(float4*)(oc + crow1 + 4) = (float4){a1[4],a1[5],a1[6],a1[7]};
      } else {
        uint4 o0, o1;
        o0.x = f2bf(a0[0]) | (f2bf(a0[1]) << 16);
        o0.y = f2bf(a0[2]) | (f2bf(a0[3]) << 16);
        o0.z = f2bf(a0[4]) | (f2bf(a0[5]) << 16);
        o0.w = f2bf(a0[6]) | (f2bf(a0[7]) << 16);
        o1.x = f2bf(a1[0]) | (f2bf(a1[1]) << 16);
        o1.y = f2bf(a1[2]) | (f2bf(a1[3]) << 16);
        o1.z = f2bf(a1[4]) | (f2bf(a1[5]) << 16);
        o1.w = f2bf(a1[6]) | (f2bf(a1[7]) << 16);
        *(uint4*)((unsigned short*)out + crow0) = o0;
        *(uint4*)((unsigned short*)out + crow1) = o1;
      }
    }
  }
}

// ================= fallback: single kernel (passes @ ~101 us) =========
__global__ __launch_bounds__(512, 4) void fused_kernel(
    const void* __restrict__ queries, const void* __restrict__ keys,
    const void* __restrict__ Wa_w,   const void* __restrict__ Wa_b,
    const void* __restrict__ Ua_w,   const void* __restrict__ Ua_b,
    const void* __restrict__ Va_w,
    void* __restrict__ out)
{
  __shared__ float qp_s[FQT*QSTR];
  __shared__ float va_s[HD];
  __shared__ __align__(16) unsigned short keys_s[KTILE*KBSTR];
  __shared__ __align__(16) float kp_s[KTILE*KSTR];
  __shared__ float sc_s[FQT*TKN];
  __shared__ unsigned int flg_s[8];

  const int tid = threadIdx.x;
  if (tid < 8) flg_s[tid] = 0;
  __syncthreads();
  {
    const void* ptrs[7] = {queries, keys, Wa_w, Wa_b, Ua_w, Ua_b, Va_w};
    const int grp = tid >> 5;
    const int l   = tid & 31;
    if (grp < 7){
      const unsigned short* p = (const unsigned short*)ptrs[grp];
      unsigned short a = p[2*l], c = p[64 + 2*l];
      if (((a >> 7) & 0xFF) > 0x90 || ((c >> 7) & 0xFF) > 0x90)
        atomicOr(&flg_s[grp], 1u);
    }
  }
  __syncthreads();
  const bool fQ  = flg_s[0] != 0;
  const bool fK  = flg_s[1] != 0;
  const bool fWw = flg_s[2] != 0;
  const bool fWb = flg_s[3] != 0;
  const bool fUw = flg_s[4] != 0;
  const bool fUb = flg_s[5] != 0;
  const bool fVw = flg_s[6] != 0;

  const int lane = tid & 63;
  const int wv   = tid >> 6;
  const int ln   = lane & 15;
  const int quad = lane >> 4;
  const int b     = blockIdx.x >> 6;
  const int qbase = (blockIdx.x & 63) * FQT;

  if (tid < HD) va_s[tid] = ld1(Va_w, tid, fVw);
  {
    const int h0 = wv * 16;
    const size_t qrow = (size_t)(b*TQN + qbase + (ln & 7))*HD;
    f32x4 c = {0.f,0.f,0.f,0.f};
    #pragma unroll
    for (int ks = 0; ks < 4; ks++){
      short8 a = ld8bf(queries, qrow + ks*32 + quad*8, fQ);
      short8 w = ld8bf(Wa_w, (size_t)(h0 + ln)*HD + ks*32 + quad*8, fWw);
      c = __builtin_amdgcn_mfma_f32_16x16x32_bf16(a, w, c, 0,0,0);
    }
    const float wb = ld1(Wa_b, h0 + ln, fWb);
    #pragma unroll
    for (int r = 0; r < 4; r++){
      const int row = quad*4 + r;
      if (row < FQT) qp_s[row*QSTR + h0 + ln] = tanh_acc(c[r] + wb);
    }
  }
  short8 ub[4];
  float ubias;
  {
    const int h0 = wv * 16;
    #pragma unroll
    for (int ks = 0; ks < 4; ks++)
      ub[ks] = ld8bf(Ua_w, (size_t)(h0 + ln)*HD + ks*32 + quad*8, fUw);
    ubias = ld1(Ua_b, h0 + ln, fUb);
  }
  { // stage keys tile 0
    if (fK){
      const float4* src = (const float4*)((const float*)keys + (size_t)(b*TKN)*HD);
      #pragma unroll
      for (int j = 0; j < 4; j++){
        const int f = tid + 512*j;
        float4 v = src[f];
        const int k = f >> 5, h = (f & 31)*4;
        uint2 p;
        p.x = f2bf(v.x) | (f2bf(v.y) << 16);
        p.y = f2bf(v.z) | (f2bf(v.w) << 16);
        *(uint2*)(keys_s + k*KBSTR + h) = p;
      }
    } else {
      const uint4* src = (const uint4*)((const unsigned short*)keys + (size_t)(b*TKN)*HD);
      #pragma unroll
      for (int j = 0; j < 2; j++){
        const int f = tid + 512*j;
        uint4 v = src[f];
        const int k = f >> 4, h = (f & 15)*8;
        *(uint4*)(keys_s + k*KBSTR + h) = v;
      }
    }
  }
  __syncthreads();

  const int s8 = lane >> 3;
  const int o8 = lane & 7;
  float tqr[16], var[16], vat[16];
  {
    const float* qsrc = qp_s + wv*QSTR + o8*16;
    const float* vsrc = va_s + o8*16;
    #pragma unroll
    for (int c = 0; c < 4; c++){
      float4 t = *(const float4*)(qsrc + c*4);
      float4 v = *(const float4*)(vsrc + c*4);
      tqr[c*4+0]=t.x; tqr[c*4+1]=t.y; tqr[c*4+2]=t.z; tqr[c*4+3]=t.w;
      var[c*4+0]=v.x; var[c*4+1]=v.y; var[c*4+2]=v.z; var[c*4+3]=v.w;
      vat[c*4+0]=v.x*t.x; vat[c*4+1]=v.y*t.y; vat[c*4+2]=v.z*t.z; vat[c*4+3]=v.w*t.w;
    }
  }
  for (int kt = 0; kt < 8; kt++){
    f32x4 kc[4];
    #pragma unroll
    for (int mt = 0; mt < 4; mt++) kc[mt] = (f32x4){0.f,0.f,0.f,0.f};
    #pragma unroll
    for (int ks = 0; ks < 4; ks++){
      short8 af[4];
      #pragma unroll
      for (int mt = 0; mt < 4; mt++)
        af[mt] = *(const short8*)(keys_s + (mt*16 + ln)*KBSTR + ks*32 + quad*8);
      #pragma unroll
      for (int mt = 0; mt < 4; mt++)
        kc[mt] = __builtin_amdgcn_mfma_f32_16x16x32_bf16(af[mt], ub[ks], kc[mt], 0,0,0);
    }
    __syncthreads();
    #pragma unroll
    for (int mt = 0; mt < 4; mt++)
      #pragma unroll
      for (int r = 0; r < 4; r++)
        kp_s[(mt*16 + quad*4 + r)*KSTR + wv*16 + ln] = tanh_acc(kc[mt][r] + ubias);
    if (kt < 7){
      if (fK){
        const float4* src = (const float4*)((const float*)keys + (size_t)(b*TKN + (kt+1)*KTILE)*HD);
        #pragma unroll
        for (int j = 0; j < 4; j++){
          const int f = tid + 512*j;
          float4 v = src[f];
          const int k = f >> 5, h = (f & 31)*4;
          uint2 p;
          p.x = f2bf(v.x) | (f2bf(v.y) << 16);
          p.y = f2bf(v.z) | (f2bf(v.w) << 16);
          *(uint2*)(keys_s + k*KBSTR + h) = p;
        }
      } else {
        const uint4* src = (const uint4*)((const unsigned short*)keys + (size_t)(b*TKN + (kt+1)*KTILE)*HD);
        #pragma unroll
        for (int j = 0; j < 2; j++){
          const int f = tid + 512*j;
          uint4 v = src[f];
          const int k = f >> 4, h = (f & 15)*8;
          *(uint4*)(keys_s + k*KBSTR + h) = v;
        }
      }
    }
    __syncthreads();
    float acc[8];
    #pragma unroll
    for (int i = 0; i < 8; i++) acc[i] = 0.f;
    #pragma unroll
    for (int i = 0; i < 8; i++){
      const float* tk = kp_s + (i*8 + s8)*KSTR + o8*16;
      #pragma unroll
      for (int c = 0; c < 4; c++){
        const float4 kv = *(const float4*)(tk + c*4);
        acc[i] = fmaf(fmaf(var[c*4+0], kv.x, vat[c*4+0]),
                      __builtin_amdgcn_rcpf(fmaf(tqr[c*4+0], kv.x, 1.f)), acc[i]);
        acc[i] = fmaf(fmaf(var[c*4+1], kv.y, vat[c*4+1]),
                      __builtin_amdgcn_rcpf(fmaf(tqr[c*4+1], kv.y, 1.f)), acc[i]);
        acc[i] = fmaf(fmaf(var[c*4+2], kv.z, vat[c*4+2]),
                      __builtin_amdgcn_rcpf(fmaf(tqr[c*4+2], kv.z, 1.f)), acc[i]);
        acc[i] = fmaf(fmaf(var[c*4+3], kv.w, vat[c*4+3]),
                      __builtin_amdgcn_rcpf(fmaf(tqr[c*4+3], kv.w, 1.f)), acc[i]);
      }
    }
    #pragma unroll
    for (int i = 0; i < 8; i++){
      float a = acc[i];
      a = dpp_add<0xB1>(a);
      a = dpp_add<0x4E>(a);
      a = dpp_add<0x141>(a);
      acc[i] = a;
    }
    float sc = acc[0];
    #pragma unroll
    for (int i = 1; i < 8; i++) sc = (o8 == i) ? acc[i] : sc;
    sc_s[wv*TKN + kt*KTILE + o8*8 + s8] = sc;
  }
  __syncthreads();
  {
    float vals[8];
    float m = -1e30f;
    #pragma unroll
    for (int j = 0; j < 8; j++){
      vals[j] = sc_s[wv*TKN + lane + 64*j];
      m = fmaxf(m, vals[j]);
    }
    #pragma unroll
    for (int o = 32; o > 0; o >>= 1) m = fmaxf(m, __shfl_xor(m, o));
    float sum = 0.f;
    #pragma unroll
    for (int j = 0; j < 8; j++){
      vals[j] = __builtin_amdgcn_exp2f((vals[j]-m)*1.4426950408889634f);
      sum += vals[j];
    }
    #pragma unroll
    for (int o = 32; o > 0; o >>= 1) sum += __shfl_xor(sum, o);
    const float inv = __builtin_amdgcn_rcpf(sum);
    const size_t wbase = (size_t)NB*TQN*HD + (size_t)(b*TQN + qbase + wv)*TKN;
    #pragma unroll
    for (int j = 0; j < 8; j++){
      const float w = vals[j]*inv;
      sc_s[wv*TKN + lane + 64*j] = w;
      if (fQ) ((float*)out)[wbase + lane + 64*j] = w;
      else    ((unsigned short*)out)[wbase + lane + 64*j] = (unsigned short)f2bf(w);
    }
  }
  __syncthreads();
  {
    const int p2 = wv & 3;
    const int g2 = wv >> 2;
    const int h0 = ln * 8;
    float a0[8], a1[8];
    #pragma unroll
    for (int t = 0; t < 8; t++){ a0[t] = 0.f; a1[t] = 0.f; }
    for (int kt = 0; kt < 8; kt++){
      if (fK){
        const float4* src = (const float4*)((const float*)keys + (size_t)(b*TKN + kt*KTILE)*HD);
        #pragma unroll
        for (int j = 0; j < 4; j++){
          const int f = tid + 512*j;
          const int k = f >> 5, h = (f & 31)*4;
          *(float4*)(kp_s + k*KSTR + h) = src[f];
        }
      } else {
        const uint4* src = (const uint4*)((const unsigned short*)keys + (size_t)(b*TKN + kt*KTILE)*HD);
        #pragma unroll
        for (int j = 0; j < 2; j++){
          const int f = tid + 512*j;
          const int k = f >> 4, h = (f & 15)*8;
          uint4 v = src[f];
          float4 d0, d1;
          d0.x = lo16(v.x); d0.y = hi16(v.x); d0.z = lo16(v.y); d0.w = hi16(v.y);
          d1.x = lo16(v.z); d1.y = hi16(v.z); d1.z = lo16(v.w); d1.w = hi16(v.w);
          *(float4*)(kp_s + k*KSTR + h)     = d0;
          *(float4*)(kp_s + k*KSTR + h + 4) = d1;
        }
      }
      __syncthreads();
      const float* w0r = sc_s + (2*p2)*TKN + kt*KTILE + g2*32;
      const float* w1r = w0r + TKN;
      #pragma unroll
      for (int i = 0; i < 8; i++){
        const int k = i*4 + quad;
        const float w0 = w0r[k];
        const float w1 = w1r[k];
        const float* kr = kp_s + (g2*32 + k)*KSTR + h0;
        const float4 k0 = *(const float4*)(kr);
        const float4 k1 = *(const float4*)(kr + 4);
        a0[0]=fmaf(w0,k0.x,a0[0]); a0[1]=fmaf(w0,k0.y,a0[1]);
        a0[2]=fmaf(w0,k0.z,a0[2]); a0[3]=fmaf(w0,k0.w,a0[3]);
        a0[4]=fmaf(w0,k1.x,a0[4]); a0[5]=fmaf(w0,k1.y,a0[5]);
        a0[6]=fmaf(w0,k1.z,a0[6]); a0[7]=fmaf(w0,k1.w,a0[7]);
        a1[0]=fmaf(w1,k0.x,a1[0]); a1[1]=fmaf(w1,k0.y,a1[1]);
        a1[2]=fmaf(w1,k0.z,a1[2]); a1[3]=fmaf(w1,k0.w,a1[3]);
        a1[4]=fmaf(w1,k1.x,a1[4]); a1[5]=fmaf(w1,k1.y,a1[5]);
        a1[6]=fmaf(w1,k1.z,a1[6]); a1[7]=fmaf(w1,k1.w,a1[7]);
      }
      __syncthreads();
    }
    #pragma unroll
    for (int t = 0; t < 8; t++){
      a0[t] += __shfl_xor(a0[t], 16); a0[t] += __shfl_xor(a0[t], 32);
      a1[t] += __shfl_xor(a1[t], 16); a1[t] += __shfl_xor(a1[t], 32);
    }
    float* part = qp_s;
    if (g2 == 1 && quad == 0){
      *(float4*)(part + (2*p2  )*HD + h0    ) = (float4){a0[0],a0[1],a0[2],a0[3]};
      *(float4*)(part + (2*p2  )*HD + h0 + 4) = (float4){a0[4],a0[5],a0[6],a0[7]};
      *(float4*)(part + (2*p2+1)*HD + h0    ) = (float4){a1[0],a1[1],a1[2],a1[3]};
      *(float4*)(part + (2*p2+1)*HD + h0 + 4) = (float4){a1[4],a1[5],a1[6],a1[7]};
    }
    __syncthreads();
    if (g2 == 0 && quad == 0){
      const float4 p00 = *(const float4*)(part + (2*p2  )*HD + h0    );
      const float4 p01 = *(const float4*)(part + (2*p2  )*HD + h0 + 4);
      const float4 p10 = *(const float4*)(part + (2*p2+1)*HD + h0    );
      const float4 p11 = *(const float4*)(part + (2*p2+1)*HD + h0 + 4);
      const size_t crow0 = (size_t)(b*TQN + qbase + 2*p2    )*HD + h0;
      const size_t crow1 = (size_t)(b*TQN + qbase + 2*p2 + 1)*HD + h0;
      if (fQ){
        float* oc = (float*)out;
        *(float4*)(oc + crow0)     = (float4){a0[0]+p00.x, a0[1]+p00.y, a0[2]+p00.z, a0[3]+p00.w};
        *(float4*)(oc + crow0 + 4) = (float4){a0[4]+p01.x, a0[5]+p01.y, a0[6]+p01.z, a0[7]+p01.w};
        *(float4*)(oc + crow1)     = (float4){a1[0]+p10.x, a1[1]+p10.y, a1[2]+p10.z, a1[3]+p10.w};
        *(float4*)(oc + crow1 + 4) = (float4){a1[4]+p11.x, a1[5]+p11.y, a1[6]+p11.z, a1[7]+p11.w};
      } else {
        uint4 o0, o1;
        o0.x = f2bf(a0[0]+p00.x) | (f2bf(a0[1]+p00.y) << 16);
        o0.y = f2bf(a0[2]+p00.z) | (f2bf(a0[3]+p00.w) << 16);
        o0.z = f2bf(a0[4]+p01.x) | (f2bf(a0[5]+p01.y) << 16);
        o0.w = f2bf(a0[6]+p01.z) | (f2bf(a0[7]+p01.w) << 16);
        o1.x = f2bf(a1[0]+p10.x) | (f2bf(a1[1]+p10.y) << 16);
        o1.y = f2bf(a1[2]+p10.z) | (f2bf(a1[3]+p10.w) << 16);
        o1.z = f2bf(a1[4]+p11.x) | (f2bf(a1[5]+p11.y) << 16);
        o1.w = f2bf(a1[6]+p11.z) | (f2bf(a1[7]+p11.w) << 16);
        *(uint4*)((unsigned short*)out + crow0) = o0;
        *(uint4*)((unsigned short*)out + crow1) = o1;
      }
    }
  }
}

extern "C" void kernel_launch(void* const* d_in, const int* in_sizes, int n_in,
                              void* d_out, int out_size, void* d_ws, size_t ws_size,
                              hipStream_t stream) {
  (void)in_sizes; (void)n_in; (void)out_size;
  const size_t need = (size_t)2 * NB * TQN * HD * sizeof(unsigned short);  // 2 MB
  if (ws_size >= need){
    unsigned short* tq_gb = (unsigned short*)d_ws;
    unsigned short* tk_gb = tq_gb + (size_t)NB*TQN*HD;
    proj_kernel<<<512, 256, 0, stream>>>(d_in[0], d_in[1], d_in[2], d_in[3],
                                         d_in[4], d_in[5], tq_gb, tk_gb);
    attn_kernel<<<512, 1024, 0, stream>>>(d_in[0], d_in[1], d_in[6],
                                          tq_gb, tk_gb, d_out);
  } else {
    fused_kernel<<<512, 512, 0, stream>>>(d_in[0], d_in[1], d_in[2], d_in[3],
                                          d_in[4], d_in[5], d_in[6], d_out);
  }
}